// Round 3
// baseline (1878.883 us; speedup 1.0000x reference)
//
#include <hip/hip_runtime.h>
#include <hip/hip_bf16.h>
#include <cstddef>

#define NN 100000
#define NE 1600000
#define NG 2000
#define NS 40
#define INF 64
#define F 128
#define FFN_DIM 1024
#define NB 782            // ceil(100000/128) buckets of 128 nodes
#define SC_BLOCKS 100
#define SC_CHUNK 16000    // 100*16000 = 1.6M edges exactly

using bf16 = __hip_bfloat16;
using bf162 = __hip_bfloat162;

// ---------------- degree count ----------------
__global__ __launch_bounds__(256) void k_count(const int* __restrict__ ei, int* __restrict__ cnt){
    int e = blockIdx.x*256 + threadIdx.x;
    if (e < NE) atomicAdd(&cnt[ei[NE + e]], 1);
}

// ---------------- dinv + per-bucket edge counts (fused) ----------------
__global__ __launch_bounds__(256) void k_dinv_bcnt(const int* __restrict__ cnt, float* __restrict__ dinv,
                                                   int* __restrict__ bcnt){
    __shared__ int sd[256];
    int t = threadIdx.x;
    int i = blockIdx.x*256 + t;
    int c = (i < NN) ? cnt[i] : 0;
    if (i < NN) dinv[i] = rsqrtf((float)c + 2.0f);
    sd[t] = c; __syncthreads();
    #pragma unroll
    for (int off=64; off>=1; off>>=1){
        if ((t & 127) < off) sd[t] += sd[t+off];
        __syncthreads();
    }
    if (t == 0)   bcnt[2*blockIdx.x]   = sd[0];
    if (t == 128) bcnt[2*blockIdx.x+1] = sd[128];
}

// ---------------- scan 782 bucket counts -> bstart[783], bcursor ----------------
__global__ __launch_bounds__(1024) void k_bscan(const int* __restrict__ bcnt, int* __restrict__ bstart,
                                                int* __restrict__ bcursor){
    __shared__ int s[1024];
    int t = threadIdx.x;
    int own = (t < NB) ? bcnt[t] : 0;
    s[t] = own; __syncthreads();
    #pragma unroll
    for (int off=1; off<1024; off<<=1){
        int v = (t >= off) ? s[t-off] : 0;
        __syncthreads();
        s[t] += v;
        __syncthreads();
    }
    int excl = s[t] - own;
    if (t <= NB) bstart[t] = excl;     // bstart[782] == NE
    if (t < NB)  bcursor[t] = excl;
}

// ---------------- xws = (x @ W_gcn) * dinv[row], stored bf16 ----------------
__global__ __launch_bounds__(256) void k_xws(const float* __restrict__ x, const float* __restrict__ W,
                                             const float* __restrict__ dinv, bf16* __restrict__ xws){
    __shared__ float As[64*68];    // As[k][r], padded
    __shared__ float Bs[64*128];   // Bs[k][c]
    int t = threadIdx.x;
    int rowBase = blockIdx.x * 64;
    #pragma unroll
    for (int i = 0; i < 32; ++i){ int id = i*256 + t; Bs[id] = W[id]; }
    #pragma unroll
    for (int i = 0; i < 16; ++i){
        int id = i*256 + t; int kk = id & 63; int r = id >> 6;
        int row = rowBase + r;
        As[kk*68 + r] = (row < NN) ? x[(size_t)row*INF + kk] : 0.f;
    }
    __syncthreads();
    int c0 = (t & 31) * 4; int r0 = (t >> 5) * 8;
    float acc[8][4];
    #pragma unroll
    for (int i=0;i<8;i++) { acc[i][0]=0.f; acc[i][1]=0.f; acc[i][2]=0.f; acc[i][3]=0.f; }
    for (int kk = 0; kk < 64; ++kk){
        float4 b = *(const float4*)&Bs[kk*128 + c0];
        float4 a0 = *(const float4*)&As[kk*68 + r0];
        float4 a1 = *(const float4*)&As[kk*68 + r0 + 4];
        float av[8] = {a0.x,a0.y,a0.z,a0.w,a1.x,a1.y,a1.z,a1.w};
        #pragma unroll
        for (int i=0;i<8;i++){
            acc[i][0] += av[i]*b.x; acc[i][1] += av[i]*b.y;
            acc[i][2] += av[i]*b.z; acc[i][3] += av[i]*b.w;
        }
    }
    for (int i=0;i<8;i++){
        int row = rowBase + r0 + i;
        if (row < NN){
            float dv = dinv[row];
            for (int j=0;j<4;j++)
                xws[(size_t)row*F + c0 + j] = __float2bfloat16(acc[i][j]*dv);
        }
    }
}

// ---------------- binned scatter: pack (row<<7|col&127) into bucket regions ----------------
__global__ __launch_bounds__(1024) void k_scatter2(const int* __restrict__ ei, int* __restrict__ bcursor,
                                                   int* __restrict__ ebuf){
    __shared__ int lh[NB];
    __shared__ int lb[NB];
    int t = threadIdx.x;
    int base = blockIdx.x * SC_CHUNK;
    for (int b=t; b<NB; b+=1024) lh[b] = 0;
    __syncthreads();
    // pass 1: local histogram
    for (int i=t; i<SC_CHUNK; i+=1024){
        int c = ei[NE + base + i];
        atomicAdd(&lh[c>>7], 1);
    }
    __syncthreads();
    // reserve global runs
    for (int b=t; b<NB; b+=1024){
        int n = lh[b];
        lb[b] = n ? atomicAdd(&bcursor[b], n) : 0;
        lh[b] = 0;
    }
    __syncthreads();
    // pass 2: place
    for (int i=t; i<SC_CHUNK; i+=1024){
        int r = ei[base + i];
        int c = ei[NE + base + i];
        int b = c >> 7;
        int rk = atomicAdd(&lh[b], 1);
        ebuf[lb[b] + rk] = (r << 7) | (c & 127);
    }
}

// ---------------- bucketed aggregate: LDS accumulators, 128 nodes/block ----------------
__global__ __launch_bounds__(512) void k_agg2(const bf16* __restrict__ xws, const int* __restrict__ bstart,
                                              const float* __restrict__ dinv, const float* __restrict__ b_gcn,
                                              const float* __restrict__ bn_g, const float* __restrict__ bn_b,
                                              const int* __restrict__ ebuf, float* __restrict__ h){
    __shared__ float acc[128*F];   // 64 KB
    int t = threadIdx.x;
    int b = blockIdx.x;
    int n0 = b * 128;
    float4* acc4 = (float4*)acc;
    #pragma unroll
    for (int i=0;i<8;i++) acc4[i*512 + t] = make_float4(0.f,0.f,0.f,0.f);
    __syncthreads();
    int e0 = bstart[b], e1 = bstart[b+1];
    int wid = t >> 6, lane = t & 63;
    const bf162* xw2 = (const bf162*)xws;
    int e = e0 + wid*4;
    for (; e + 4 <= e1; e += 32){
        int v0 = ebuf[e], v1 = ebuf[e+1], v2 = ebuf[e+2], v3 = ebuf[e+3];
        float2 f0 = __bfloat1622float2(xw2[(size_t)(v0>>7)*64 + lane]);
        float2 f1 = __bfloat1622float2(xw2[(size_t)(v1>>7)*64 + lane]);
        float2 f2 = __bfloat1622float2(xw2[(size_t)(v2>>7)*64 + lane]);
        float2 f3 = __bfloat1622float2(xw2[(size_t)(v3>>7)*64 + lane]);
        int c0 = (v0 & 127) << 7, c1 = (v1 & 127) << 7, c2 = (v2 & 127) << 7, c3 = (v3 & 127) << 7;
        atomicAdd(&acc[c0 + 2*lane], f0.x); atomicAdd(&acc[c0 + 2*lane + 1], f0.y);
        atomicAdd(&acc[c1 + 2*lane], f1.x); atomicAdd(&acc[c1 + 2*lane + 1], f1.y);
        atomicAdd(&acc[c2 + 2*lane], f2.x); atomicAdd(&acc[c2 + 2*lane + 1], f2.y);
        atomicAdd(&acc[c3 + 2*lane], f3.x); atomicAdd(&acc[c3 + 2*lane + 1], f3.y);
    }
    #pragma unroll
    for (int j=0;j<4;j++){
        int ee = e + j;
        if (ee < e1){
            int v = ebuf[ee];
            float2 f0 = __bfloat1622float2(xw2[(size_t)(v>>7)*64 + lane]);
            int c0 = (v & 127) << 7;
            atomicAdd(&acc[c0 + 2*lane], f0.x); atomicAdd(&acc[c0 + 2*lane + 1], f0.y);
        }
    }
    __syncthreads();
    // epilogue: h = relu((dinv*(acc + 2*xws_self) + b_gcn) * bns * bn_g + bn_b), linear float4 stores
    float bns = rsqrtf(1.f + 1e-5f);
    for (int i=t; i<4096; i+=512){
        int nl = i >> 5;
        int node = n0 + nl;
        if (node >= NN) continue;
        int f2 = (i & 31) * 2;          // bf162 index (covers feats 4f..4f+3)
        float4 a = acc4[i];
        float dv = dinv[node];
        float2 s01 = __bfloat1622float2(xw2[(size_t)node*64 + f2]);
        float2 s23 = __bfloat1622float2(xw2[(size_t)node*64 + f2 + 1]);
        int f = f2 * 2;
        float4 o;
        o.x = fmaxf((dv*(a.x + 2.f*s01.x) + b_gcn[f])   * bns * bn_g[f]   + bn_b[f],   0.f);
        o.y = fmaxf((dv*(a.y + 2.f*s01.y) + b_gcn[f+1]) * bns * bn_g[f+1] + bn_b[f+1], 0.f);
        o.z = fmaxf((dv*(a.z + 2.f*s23.x) + b_gcn[f+2]) * bns * bn_g[f+2] + bn_b[f+2], 0.f);
        o.w = fmaxf((dv*(a.w + 2.f*s23.y) + b_gcn[f+3]) * bns * bn_g[f+3] + bn_b[f+3], 0.f);
        *(float4*)&h[(size_t)node*F + f] = o;
    }
}

// ---------------- mean pool (50 nodes/graph) ----------------
__global__ __launch_bounds__(256) void k_pool(const float* __restrict__ h, float* __restrict__ z){
    int t = threadIdx.x;
    int g = blockIdx.x*2 + (t>>7);
    int f = t & 127;
    float s = 0.f;
    const float* p = h + (size_t)g*50*F + f;
    #pragma unroll 5
    for (int i=0;i<50;i++) s += p[i*F];
    z[g*F+f] = s / 50.0f;
}

// ---------------- LayerNorm (optional residual add) ----------------
__global__ __launch_bounds__(256) void k_ln(const float* __restrict__ A, const float* __restrict__ R,
                                            const float* __restrict__ g, const float* __restrict__ b,
                                            float* __restrict__ out){
    int t = threadIdx.x; int lane = t&63;
    int row = blockIdx.x*4 + (t>>6);
    int i0 = row*F + 2*lane;
    float x0 = A[i0], x1 = A[i0+1];
    if (R){ x0 += R[i0]; x1 += R[i0+1]; }
    float s = x0+x1;
    for (int off=1; off<64; off<<=1) s += __shfl_xor(s, off);
    float m = s * (1.f/128.f);
    float d0 = x0-m, d1 = x1-m;
    float vv = d0*d0 + d1*d1;
    for (int off=1; off<64; off<<=1) vv += __shfl_xor(vv, off);
    float rs = rsqrtf(vv*(1.f/128.f) + 1e-5f);
    out[i0]   = d0*rs*g[2*lane]   + b[2*lane];
    out[i0+1] = d1*rs*g[2*lane+1] + b[2*lane+1];
}

// ---------------- generic small GEMM: C = A[MxK] @ B[KxN] + bias, opt ReLU ----------------
template<int RELU>
__global__ __launch_bounds__(256) void k_gemm(const float* __restrict__ A, const float* __restrict__ B,
                                              const float* __restrict__ bias, float* __restrict__ C,
                                              int M, int K, int Nc){
    __shared__ float As[32*68];
    __shared__ float Bs[32*64];
    int t = threadIdx.x;
    int rowBase = blockIdx.x*64;
    int colBase = blockIdx.y*64;
    int c0 = (t&15)*4, r0 = (t>>4)*4;
    float acc[4][4];
    #pragma unroll
    for (int i=0;i<4;i++){ acc[i][0]=0.f; acc[i][1]=0.f; acc[i][2]=0.f; acc[i][3]=0.f; }
    for (int kb=0; kb<K; kb+=32){
        #pragma unroll
        for (int i=0;i<8;i++){
            int id = i*256+t; int kk = id&31; int r = id>>5;
            int row = rowBase + r;
            As[kk*68+r] = (row<M) ? A[(size_t)row*K + kb + kk] : 0.f;
        }
        #pragma unroll
        for (int i=0;i<8;i++){
            int id = i*256+t; int c = id&63; int kk = id>>6;
            Bs[kk*64+c] = B[(size_t)(kb+kk)*Nc + colBase + c];
        }
        __syncthreads();
        for (int kk=0;kk<32;kk++){
            float4 a = *(const float4*)&As[kk*68+r0];
            float4 b = *(const float4*)&Bs[kk*64+c0];
            float av[4]={a.x,a.y,a.z,a.w}; float bv[4]={b.x,b.y,b.z,b.w};
            #pragma unroll
            for(int i=0;i<4;i++)
                #pragma unroll
                for(int j=0;j<4;j++) acc[i][j] += av[i]*bv[j];
        }
        __syncthreads();
    }
    for (int i=0;i<4;i++){
        int row = rowBase + r0 + i;
        if (row < M){
            for (int j=0;j<4;j++){
                float v = acc[i][j] + bias[colBase+c0+j];
                if (RELU) v = fmaxf(v, 0.f);
                C[(size_t)row*Nc + colBase + c0 + j] = v;
            }
        }
    }
}

// ---------------- attention: one block per (set, head) ----------------
__global__ __launch_bounds__(256) void k_attn(const float* __restrict__ q, const float* __restrict__ k,
                                              const float* __restrict__ v, float* __restrict__ o){
    __shared__ float Qs[1600], Ks[1600], Vs[1600], Sc[2500];
    int t = threadIdx.x;
    int s = blockIdx.x >> 2; int hh = blockIdx.x & 3;
    for (int idx=t; idx<1600; idx+=256){
        int i = idx>>5, d = idx&31;
        size_t gi = (size_t)(s*50+i)*F + hh*32 + d;
        Qs[idx]=q[gi]; Ks[idx]=k[gi]; Vs[idx]=v[gi];
    }
    __syncthreads();
    for (int idx=t; idx<2500; idx+=256){
        int qi = idx/50, ki = idx%50;
        float acc=0.f;
        #pragma unroll 8
        for (int d=0;d<32;d++) acc += Qs[qi*32+d]*Ks[ki*32+d];
        Sc[idx] = acc * 0.17677669529663687f;   // 1/sqrt(32)
    }
    __syncthreads();
    if (t < 50){
        float m=-1e30f;
        for (int j=0;j<50;j++) m = fmaxf(m, Sc[t*50+j]);
        float sum=0.f;
        for (int j=0;j<50;j++){ float e=__expf(Sc[t*50+j]-m); Sc[t*50+j]=e; sum+=e; }
        float inv = 1.f/sum;
        for (int j=0;j<50;j++) Sc[t*50+j] *= inv;
    }
    __syncthreads();
    for (int idx=t; idx<1600; idx+=256){
        int qi = idx>>5, d = idx&31;
        float acc=0.f;
        #pragma unroll 10
        for (int ki=0;ki<50;ki++) acc += Sc[qi*50+ki]*Vs[ki*32+d];
        o[(size_t)(s*50+qi)*F + hh*32 + d] = acc;
    }
}

// ---------------- gate GEMM (h @ Wg_top) + sigmoid blend epilogue -> out fp32 ----------------
__global__ __launch_bounds__(256) void k_gate(const float* __restrict__ h, const float* __restrict__ Wg,
                                              const float* __restrict__ gsi, const float* __restrict__ zd2,
                                              float* __restrict__ out){
    __shared__ float As[32*68];
    __shared__ float Bs[32*64];
    int t = threadIdx.x;
    int rowBase = blockIdx.x*64;
    int colBase = blockIdx.y*64;
    int c0=(t&15)*4, r0=(t>>4)*4;
    float acc[4][4];
    #pragma unroll
    for (int i=0;i<4;i++){ acc[i][0]=0.f; acc[i][1]=0.f; acc[i][2]=0.f; acc[i][3]=0.f; }
    for (int kb=0; kb<F; kb+=32){
        #pragma unroll
        for (int i=0;i<8;i++){
            int id=i*256+t; int kk=id&31; int r=id>>5;
            int row=rowBase+r;
            As[kk*68+r]=(row<NN)?h[(size_t)row*F+kb+kk]:0.f;
        }
        #pragma unroll
        for (int i=0;i<8;i++){
            int id=i*256+t; int c=id&63; int kk=id>>6;
            Bs[kk*64+c]=Wg[(size_t)(kb+kk)*F + colBase + c];  // top 128 rows of Wg
        }
        __syncthreads();
        for (int kk=0;kk<32;kk++){
            float4 a=*(const float4*)&As[kk*68+r0];
            float4 b=*(const float4*)&Bs[kk*64+c0];
            float av[4]={a.x,a.y,a.z,a.w}, bv[4]={b.x,b.y,b.z,b.w};
            #pragma unroll
            for(int i=0;i<4;i++)
                #pragma unroll
                for(int j=0;j<4;j++) acc[i][j]+=av[i]*bv[j];
        }
        __syncthreads();
    }
    for (int i=0;i<4;i++){
        int row=rowBase+r0+i;
        if (row<NN){
            int g = row/50;
            for (int j=0;j<4;j++){
                int col = colBase+c0+j;
                float L = acc[i][j] + gsi[g*F+col];
                float gate = 1.f/(1.f+__expf(-L));
                float si = zd2[g*F+col];
                float hv = h[(size_t)row*F+col];
                out[(size_t)row*F+col] = gate*si + (1.f-gate)*hv;
            }
        }
    }
}

extern "C" void kernel_launch(void* const* d_in, const int* in_sizes, int n_in,
                              void* d_out, int out_size, void* d_ws, size_t ws_size,
                              hipStream_t stream) {
    const float* x      = (const float*)d_in[0];
    const int*   ei     = (const int*)d_in[1];
    const float* W_gcn  = (const float*)d_in[4];
    const float* b_gcn  = (const float*)d_in[5];
    const float* bn_g   = (const float*)d_in[6];
    const float* bn_b   = (const float*)d_in[7];
    const float* lnpre_g= (const float*)d_in[8];
    const float* lnpre_b= (const float*)d_in[9];
    const float* Wq     = (const float*)d_in[10];
    const float* bq     = (const float*)d_in[11];
    const float* Wk     = (const float*)d_in[12];
    const float* bk     = (const float*)d_in[13];
    const float* Wv     = (const float*)d_in[14];
    const float* bv     = (const float*)d_in[15];
    const float* Wo     = (const float*)d_in[16];
    const float* bo     = (const float*)d_in[17];
    const float* ln1_g  = (const float*)d_in[18];
    const float* ln1_b  = (const float*)d_in[19];
    const float* W1     = (const float*)d_in[20];
    const float* b1     = (const float*)d_in[21];
    const float* W2     = (const float*)d_in[22];
    const float* b2     = (const float*)d_in[23];
    const float* ln2_g  = (const float*)d_in[24];
    const float* ln2_b  = (const float*)d_in[25];
    const float* Wg     = (const float*)d_in[26];
    const float* bg     = (const float*)d_in[27];
    float* out = (float*)d_out;
    char* ws = (char*)d_ws;

    // workspace layout
    size_t o = 0;
    bf16*  xws   = (bf16*)(ws + o);  o += (size_t)NN*F*2;            // 25.6 MB
    float* h     = (float*)(ws + o); o += (size_t)NN*F*4;            // 51.2 MB
    int*   cnt   = (int*)(ws + o);   o += (size_t)NN*4;
    int*   ebuf  = (int*)(ws + o);   o += (size_t)NE*4;              // 6.4 MB
    float* dinv  = (float*)(ws + o); o += (size_t)NN*4;
    int*   bcnt  = (int*)(ws + o);   o += 1024*4;
    int*   bstart= (int*)(ws + o);   o += 1024*4;
    int*   bcursor=(int*)(ws + o);   o += 1024*4;
    float* z     = (float*)(ws + o); o += (size_t)NG*F*4;
    float* zn    = (float*)(ws + o); o += (size_t)NG*F*4;
    float* qb    = (float*)(ws + o); o += (size_t)NG*F*4;
    float* kb2   = (float*)(ws + o); o += (size_t)NG*F*4;
    float* vb    = (float*)(ws + o); o += (size_t)NG*F*4;
    float* ao    = (float*)(ws + o); o += (size_t)NG*F*4;
    float* ap    = (float*)(ws + o); o += (size_t)NG*F*4;
    float* zd1   = (float*)(ws + o); o += (size_t)NG*F*4;
    float* ffn1  = (float*)(ws + o); o += (size_t)NG*FFN_DIM*4;      // 8.2 MB
    float* ffn2  = (float*)(ws + o); o += (size_t)NG*F*4;
    float* zd2   = (float*)(ws + o); o += (size_t)NG*F*4;
    float* gsi   = (float*)(ws + o); o += (size_t)NG*F*4;

    // ---- GCN phase ----
    hipMemsetAsync(cnt, 0, (size_t)NN*4, stream);
    k_count<<<(NE+255)/256, 256, 0, stream>>>(ei, cnt);
    k_dinv_bcnt<<<(NN+255)/256, 256, 0, stream>>>(cnt, dinv, bcnt);
    k_bscan<<<1, 1024, 0, stream>>>(bcnt, bstart, bcursor);
    k_xws<<<(NN+63)/64, 256, 0, stream>>>(x, W_gcn, dinv, xws);
    k_scatter2<<<SC_BLOCKS, 1024, 0, stream>>>(ei, bcursor, ebuf);
    k_agg2<<<NB, 512, 0, stream>>>(xws, bstart, dinv, b_gcn, bn_g, bn_b, ebuf, h);

    // ---- pool + set transformer (fp32, tiny) ----
    k_pool<<<NG/2, 256, 0, stream>>>(h, z);
    k_ln<<<NG/4, 256, 0, stream>>>(z, nullptr, lnpre_g, lnpre_b, zn);
    dim3 g2(32, 2);
    k_gemm<0><<<g2, 256, 0, stream>>>(zn, Wq, bq, qb, NG, F, F);
    k_gemm<0><<<g2, 256, 0, stream>>>(zn, Wk, bk, kb2, NG, F, F);
    k_gemm<0><<<g2, 256, 0, stream>>>(zn, Wv, bv, vb, NG, F, F);
    k_attn<<<NS*4, 256, 0, stream>>>(qb, kb2, vb, ao);
    k_gemm<0><<<g2, 256, 0, stream>>>(ao, Wo, bo, ap, NG, F, F);
    k_ln<<<NG/4, 256, 0, stream>>>(z, ap, ln1_g, ln1_b, zd1);
    dim3 gffn1(32, 16);
    k_gemm<1><<<gffn1, 256, 0, stream>>>(zd1, W1, b1, ffn1, NG, F, FFN_DIM);
    k_gemm<0><<<g2, 256, 0, stream>>>(ffn1, W2, b2, ffn2, NG, FFN_DIM, F);
    k_ln<<<NG/4, 256, 0, stream>>>(zd1, ffn2, ln2_g, ln2_b, zd2);
    k_gemm<0><<<g2, 256, 0, stream>>>(zd2, Wg + (size_t)F*F, bg, gsi, NG, F, F);

    // ---- gated fusion -> output ----
    dim3 ggate((NN+63)/64, 2);
    k_gate<<<ggate, 256, 0, stream>>>(h, Wg, gsi, zd2, out);
}

// Round 4
// 632.893 us; speedup vs baseline: 2.9687x; 2.9687x over previous
//
#include <hip/hip_runtime.h>
#include <hip/hip_bf16.h>
#include <cstddef>

#define NN 100000
#define NE 1600000
#define NG 2000
#define NS 40
#define INF 64
#define F 128
#define FFN_DIM 1024
#define NB 782            // ceil(100000/128) buckets of 128 nodes
#define SC_BLOCKS 100
#define SC_CHUNK 16000    // 100*16000 = 1.6M edges exactly

using bf16 = __hip_bfloat16;
using bf162 = __hip_bfloat162;

// ---------------- degree count ----------------
__global__ __launch_bounds__(256) void k_count(const int* __restrict__ ei, int* __restrict__ cnt){
    int e = blockIdx.x*256 + threadIdx.x;
    if (e < NE) atomicAdd(&cnt[ei[NE + e]], 1);
}

// ---------------- dinv + per-bucket edge counts (fused) ----------------
__global__ __launch_bounds__(256) void k_dinv_bcnt(const int* __restrict__ cnt, float* __restrict__ dinv,
                                                   int* __restrict__ bcnt){
    __shared__ int sd[256];
    int t = threadIdx.x;
    int i = blockIdx.x*256 + t;
    int c = (i < NN) ? cnt[i] : 0;
    if (i < NN) dinv[i] = rsqrtf((float)c + 2.0f);
    sd[t] = c; __syncthreads();
    #pragma unroll
    for (int off=64; off>=1; off>>=1){
        if ((t & 127) < off) sd[t] += sd[t+off];
        __syncthreads();
    }
    if (t == 0)   bcnt[2*blockIdx.x]   = sd[0];
    if (t == 128) bcnt[2*blockIdx.x+1] = sd[128];
}

// ---------------- scan 782 bucket counts -> bstart[783], bcursor ----------------
__global__ __launch_bounds__(1024) void k_bscan(const int* __restrict__ bcnt, int* __restrict__ bstart,
                                                int* __restrict__ bcursor){
    __shared__ int s[1024];
    int t = threadIdx.x;
    int own = (t < NB) ? bcnt[t] : 0;
    s[t] = own; __syncthreads();
    #pragma unroll
    for (int off=1; off<1024; off<<=1){
        int v = (t >= off) ? s[t-off] : 0;
        __syncthreads();
        s[t] += v;
        __syncthreads();
    }
    int excl = s[t] - own;
    if (t <= NB) bstart[t] = excl;     // bstart[782] == NE
    if (t < NB)  bcursor[t] = excl;
}

// ---------------- xws = (x @ W_gcn) * dinv[row], stored bf16 ----------------
__global__ __launch_bounds__(256) void k_xws(const float* __restrict__ x, const float* __restrict__ W,
                                             const float* __restrict__ dinv, bf16* __restrict__ xws){
    __shared__ float As[64*68];    // As[k][r], padded
    __shared__ float Bs[64*128];   // Bs[k][c]
    int t = threadIdx.x;
    int rowBase = blockIdx.x * 64;
    #pragma unroll
    for (int i = 0; i < 32; ++i){ int id = i*256 + t; Bs[id] = W[id]; }
    #pragma unroll
    for (int i = 0; i < 16; ++i){
        int id = i*256 + t; int kk = id & 63; int r = id >> 6;
        int row = rowBase + r;
        As[kk*68 + r] = (row < NN) ? x[(size_t)row*INF + kk] : 0.f;
    }
    __syncthreads();
    int c0 = (t & 31) * 4; int r0 = (t >> 5) * 8;
    float acc[8][4];
    #pragma unroll
    for (int i=0;i<8;i++) { acc[i][0]=0.f; acc[i][1]=0.f; acc[i][2]=0.f; acc[i][3]=0.f; }
    for (int kk = 0; kk < 64; ++kk){
        float4 b = *(const float4*)&Bs[kk*128 + c0];
        float4 a0 = *(const float4*)&As[kk*68 + r0];
        float4 a1 = *(const float4*)&As[kk*68 + r0 + 4];
        float av[8] = {a0.x,a0.y,a0.z,a0.w,a1.x,a1.y,a1.z,a1.w};
        #pragma unroll
        for (int i=0;i<8;i++){
            acc[i][0] += av[i]*b.x; acc[i][1] += av[i]*b.y;
            acc[i][2] += av[i]*b.z; acc[i][3] += av[i]*b.w;
        }
    }
    for (int i=0;i<8;i++){
        int row = rowBase + r0 + i;
        if (row < NN){
            float dv = dinv[row];
            for (int j=0;j<4;j++)
                xws[(size_t)row*F + c0 + j] = __float2bfloat16(acc[i][j]*dv);
        }
    }
}

// ---------------- binned scatter: pack (row<<7|col&127) into bucket regions ----------------
__global__ __launch_bounds__(1024) void k_scatter2(const int* __restrict__ ei, int* __restrict__ bcursor,
                                                   int* __restrict__ ebuf){
    __shared__ int lh[NB];
    __shared__ int lb[NB];
    int t = threadIdx.x;
    int base = blockIdx.x * SC_CHUNK;
    for (int b=t; b<NB; b+=1024) lh[b] = 0;
    __syncthreads();
    // pass 1: local histogram
    for (int i=t; i<SC_CHUNK; i+=1024){
        int c = ei[NE + base + i];
        atomicAdd(&lh[c>>7], 1);
    }
    __syncthreads();
    // reserve global runs
    for (int b=t; b<NB; b+=1024){
        int n = lh[b];
        lb[b] = n ? atomicAdd(&bcursor[b], n) : 0;
        lh[b] = 0;
    }
    __syncthreads();
    // pass 2: place
    for (int i=t; i<SC_CHUNK; i+=1024){
        int r = ei[base + i];
        int c = ei[NE + base + i];
        int b = c >> 7;
        int rk = atomicAdd(&lh[b], 1);
        ebuf[lb[b] + rk] = (r << 7) | (c & 127);
    }
}

// ---------------- per-bucket counting sort -> node-sorted rows + per-node CSR starts ----------------
__global__ __launch_bounds__(256) void k_sort(const int* __restrict__ ebuf, const int* __restrict__ bstart,
                                              const int* __restrict__ cnt, int* __restrict__ nstart,
                                              int* __restrict__ ebuf2){
    __shared__ int s[128];
    __shared__ int lcur[128];
    int t = threadIdx.x;
    int b = blockIdx.x;
    int n0 = b * 128;
    int node = n0 + t;
    int c = 0;
    if (t < 128) c = (node < NN) ? cnt[node] : 0;
    if (t < 128) s[t] = c;
    __syncthreads();
    #pragma unroll
    for (int off=1; off<128; off<<=1){
        int v = (t >= off && t < 128) ? s[t-off] : 0;
        __syncthreads();
        if (t < 128) s[t] += v;
        __syncthreads();
    }
    int e0 = bstart[b];
    if (t < 128){
        int excl = s[t] - c;
        lcur[t] = excl;
        if (node < NN) nstart[node] = e0 + excl;
    }
    __syncthreads();
    int nE = bstart[b+1] - e0;
    for (int i=t; i<nE; i+=256){
        int v = ebuf[e0 + i];
        int nl = v & 127;
        int rk = atomicAdd(&lcur[nl], 1);
        ebuf2[e0 + rk] = v >> 7;     // row index
    }
}

// ---------------- per-node CSR gather + GCN epilogue + BN + ReLU -> h (fp32) ----------------
__global__ __launch_bounds__(256) void k_agg3(const bf16* __restrict__ xws, const int* __restrict__ nstart,
                                              const int* __restrict__ cnt, const float* __restrict__ dinv,
                                              const float* __restrict__ b_gcn, const float* __restrict__ bn_g,
                                              const float* __restrict__ bn_b, const int* __restrict__ ebuf2,
                                              float* __restrict__ h){
    int t = threadIdx.x; int lane = t & 63;
    int node = blockIdx.x*4 + (t>>6);
    int s0 = nstart[node]; int dg = cnt[node]; float dv = dinv[node];
    const bf162* xw2 = (const bf162*)xws;
    float a0=0.f, a1=0.f;
    int j=0;
    for (; j+4<=dg; j+=4){
        int r0 = ebuf2[s0+j], r1 = ebuf2[s0+j+1], r2 = ebuf2[s0+j+2], r3 = ebuf2[s0+j+3];
        float2 f0 = __bfloat1622float2(xw2[(size_t)r0*64 + lane]);
        float2 f1 = __bfloat1622float2(xw2[(size_t)r1*64 + lane]);
        float2 f2 = __bfloat1622float2(xw2[(size_t)r2*64 + lane]);
        float2 f3 = __bfloat1622float2(xw2[(size_t)r3*64 + lane]);
        a0 += (f0.x + f1.x) + (f2.x + f3.x);
        a1 += (f0.y + f1.y) + (f2.y + f3.y);
    }
    for (; j<dg; ++j){
        int r0 = ebuf2[s0+j];
        float2 f0 = __bfloat1622float2(xw2[(size_t)r0*64 + lane]);
        a0 += f0.x; a1 += f0.y;
    }
    float2 fs = __bfloat1622float2(xw2[(size_t)node*64 + lane]);
    float p0 = dv*(a0 + 2.f*fs.x) + b_gcn[2*lane];
    float p1 = dv*(a1 + 2.f*fs.y) + b_gcn[2*lane+1];
    float bns = rsqrtf(1.f + 1e-5f);
    p0 = p0*bns*bn_g[2*lane]   + bn_b[2*lane];
    p1 = p1*bns*bn_g[2*lane+1] + bn_b[2*lane+1];
    h[(size_t)node*F + 2*lane]   = fmaxf(p0, 0.f);
    h[(size_t)node*F + 2*lane+1] = fmaxf(p1, 0.f);
}

// ---------------- mean pool (50 nodes/graph) ----------------
__global__ __launch_bounds__(256) void k_pool(const float* __restrict__ h, float* __restrict__ z){
    int t = threadIdx.x;
    int g = blockIdx.x*2 + (t>>7);
    int f = t & 127;
    float s = 0.f;
    const float* p = h + (size_t)g*50*F + f;
    #pragma unroll 5
    for (int i=0;i<50;i++) s += p[i*F];
    z[g*F+f] = s / 50.0f;
}

// ---------------- LayerNorm (optional residual add) ----------------
__global__ __launch_bounds__(256) void k_ln(const float* __restrict__ A, const float* __restrict__ R,
                                            const float* __restrict__ g, const float* __restrict__ b,
                                            float* __restrict__ out){
    int t = threadIdx.x; int lane = t&63;
    int row = blockIdx.x*4 + (t>>6);
    int i0 = row*F + 2*lane;
    float x0 = A[i0], x1 = A[i0+1];
    if (R){ x0 += R[i0]; x1 += R[i0+1]; }
    float s = x0+x1;
    for (int off=1; off<64; off<<=1) s += __shfl_xor(s, off);
    float m = s * (1.f/128.f);
    float d0 = x0-m, d1 = x1-m;
    float vv = d0*d0 + d1*d1;
    for (int off=1; off<64; off<<=1) vv += __shfl_xor(vv, off);
    float rs = rsqrtf(vv*(1.f/128.f) + 1e-5f);
    out[i0]   = d0*rs*g[2*lane]   + b[2*lane];
    out[i0+1] = d1*rs*g[2*lane+1] + b[2*lane+1];
}

// ---------------- generic small GEMM: C = A[MxK] @ B[KxN] + bias, opt ReLU ----------------
template<int RELU>
__global__ __launch_bounds__(256) void k_gemm(const float* __restrict__ A, const float* __restrict__ B,
                                              const float* __restrict__ bias, float* __restrict__ C,
                                              int M, int K, int Nc){
    __shared__ float As[32*68];
    __shared__ float Bs[32*64];
    int t = threadIdx.x;
    int rowBase = blockIdx.x*64;
    int colBase = blockIdx.y*64;
    int c0 = (t&15)*4, r0 = (t>>4)*4;
    float acc[4][4];
    #pragma unroll
    for (int i=0;i<4;i++){ acc[i][0]=0.f; acc[i][1]=0.f; acc[i][2]=0.f; acc[i][3]=0.f; }
    for (int kb=0; kb<K; kb+=32){
        #pragma unroll
        for (int i=0;i<8;i++){
            int id = i*256+t; int kk = id&31; int r = id>>5;
            int row = rowBase + r;
            As[kk*68+r] = (row<M) ? A[(size_t)row*K + kb + kk] : 0.f;
        }
        #pragma unroll
        for (int i=0;i<8;i++){
            int id = i*256+t; int c = id&63; int kk = id>>6;
            Bs[kk*64+c] = B[(size_t)(kb+kk)*Nc + colBase + c];
        }
        __syncthreads();
        for (int kk=0;kk<32;kk++){
            float4 a = *(const float4*)&As[kk*68+r0];
            float4 b = *(const float4*)&Bs[kk*64+c0];
            float av[4]={a.x,a.y,a.z,a.w}; float bv[4]={b.x,b.y,b.z,b.w};
            #pragma unroll
            for(int i=0;i<4;i++)
                #pragma unroll
                for(int j=0;j<4;j++) acc[i][j] += av[i]*bv[j];
        }
        __syncthreads();
    }
    for (int i=0;i<4;i++){
        int row = rowBase + r0 + i;
        if (row < M){
            for (int j=0;j<4;j++){
                float v = acc[i][j] + bias[colBase+c0+j];
                if (RELU) v = fmaxf(v, 0.f);
                C[(size_t)row*Nc + colBase + c0 + j] = v;
            }
        }
    }
}

// ---------------- attention: one block per (set, head) ----------------
__global__ __launch_bounds__(256) void k_attn(const float* __restrict__ q, const float* __restrict__ k,
                                              const float* __restrict__ v, float* __restrict__ o){
    __shared__ float Qs[1600], Ks[1600], Vs[1600], Sc[2500];
    int t = threadIdx.x;
    int s = blockIdx.x >> 2; int hh = blockIdx.x & 3;
    for (int idx=t; idx<1600; idx+=256){
        int i = idx>>5, d = idx&31;
        size_t gi = (size_t)(s*50+i)*F + hh*32 + d;
        Qs[idx]=q[gi]; Ks[idx]=k[gi]; Vs[idx]=v[gi];
    }
    __syncthreads();
    for (int idx=t; idx<2500; idx+=256){
        int qi = idx/50, ki = idx%50;
        float acc=0.f;
        #pragma unroll 8
        for (int d=0;d<32;d++) acc += Qs[qi*32+d]*Ks[ki*32+d];
        Sc[idx] = acc * 0.17677669529663687f;   // 1/sqrt(32)
    }
    __syncthreads();
    if (t < 50){
        float m=-1e30f;
        for (int j=0;j<50;j++) m = fmaxf(m, Sc[t*50+j]);
        float sum=0.f;
        for (int j=0;j<50;j++){ float e=__expf(Sc[t*50+j]-m); Sc[t*50+j]=e; sum+=e; }
        float inv = 1.f/sum;
        for (int j=0;j<50;j++) Sc[t*50+j] *= inv;
    }
    __syncthreads();
    for (int idx=t; idx<1600; idx+=256){
        int qi = idx>>5, d = idx&31;
        float acc=0.f;
        #pragma unroll 10
        for (int ki=0;ki<50;ki++) acc += Sc[qi*50+ki]*Vs[ki*32+d];
        o[(size_t)(s*50+qi)*F + hh*32 + d] = acc;
    }
}

// ---------------- gate GEMM (h @ Wg_top) + sigmoid blend epilogue -> out fp32 ----------------
__global__ __launch_bounds__(256) void k_gate(const float* __restrict__ h, const float* __restrict__ Wg,
                                              const float* __restrict__ gsi, const float* __restrict__ zd2,
                                              float* __restrict__ out){
    __shared__ float As[32*68];
    __shared__ float Bs[32*64];
    int t = threadIdx.x;
    int rowBase = blockIdx.x*64;
    int colBase = blockIdx.y*64;
    int c0=(t&15)*4, r0=(t>>4)*4;
    float acc[4][4];
    #pragma unroll
    for (int i=0;i<4;i++){ acc[i][0]=0.f; acc[i][1]=0.f; acc[i][2]=0.f; acc[i][3]=0.f; }
    for (int kb=0; kb<F; kb+=32){
        #pragma unroll
        for (int i=0;i<8;i++){
            int id=i*256+t; int kk=id&31; int r=id>>5;
            int row=rowBase+r;
            As[kk*68+r]=(row<NN)?h[(size_t)row*F+kb+kk]:0.f;
        }
        #pragma unroll
        for (int i=0;i<8;i++){
            int id=i*256+t; int c=id&63; int kk=id>>6;
            Bs[kk*64+c]=Wg[(size_t)(kb+kk)*F + colBase + c];  // top 128 rows of Wg
        }
        __syncthreads();
        for (int kk=0;kk<32;kk++){
            float4 a=*(const float4*)&As[kk*68+r0];
            float4 b=*(const float4*)&Bs[kk*64+c0];
            float av[4]={a.x,a.y,a.z,a.w}, bv[4]={b.x,b.y,b.z,b.w};
            #pragma unroll
            for(int i=0;i<4;i++)
                #pragma unroll
                for(int j=0;j<4;j++) acc[i][j]+=av[i]*bv[j];
        }
        __syncthreads();
    }
    for (int i=0;i<4;i++){
        int row=rowBase+r0+i;
        if (row<NN){
            int g = row/50;
            for (int j=0;j<4;j++){
                int col = colBase+c0+j;
                float L = acc[i][j] + gsi[g*F+col];
                float gate = 1.f/(1.f+__expf(-L));
                float si = zd2[g*F+col];
                float hv = h[(size_t)row*F+col];
                out[(size_t)row*F+col] = gate*si + (1.f-gate)*hv;
            }
        }
    }
}

extern "C" void kernel_launch(void* const* d_in, const int* in_sizes, int n_in,
                              void* d_out, int out_size, void* d_ws, size_t ws_size,
                              hipStream_t stream) {
    const float* x      = (const float*)d_in[0];
    const int*   ei     = (const int*)d_in[1];
    const float* W_gcn  = (const float*)d_in[4];
    const float* b_gcn  = (const float*)d_in[5];
    const float* bn_g   = (const float*)d_in[6];
    const float* bn_b   = (const float*)d_in[7];
    const float* lnpre_g= (const float*)d_in[8];
    const float* lnpre_b= (const float*)d_in[9];
    const float* Wq     = (const float*)d_in[10];
    const float* bq     = (const float*)d_in[11];
    const float* Wk     = (const float*)d_in[12];
    const float* bk     = (const float*)d_in[13];
    const float* Wv     = (const float*)d_in[14];
    const float* bv     = (const float*)d_in[15];
    const float* Wo     = (const float*)d_in[16];
    const float* bo     = (const float*)d_in[17];
    const float* ln1_g  = (const float*)d_in[18];
    const float* ln1_b  = (const float*)d_in[19];
    const float* W1     = (const float*)d_in[20];
    const float* b1     = (const float*)d_in[21];
    const float* W2     = (const float*)d_in[22];
    const float* b2     = (const float*)d_in[23];
    const float* ln2_g  = (const float*)d_in[24];
    const float* ln2_b  = (const float*)d_in[25];
    const float* Wg     = (const float*)d_in[26];
    const float* bg     = (const float*)d_in[27];
    float* out = (float*)d_out;
    char* ws = (char*)d_ws;

    // workspace layout
    size_t o = 0;
    bf16*  xws   = (bf16*)(ws + o);  o += (size_t)NN*F*2;            // 25.6 MB
    float* h     = (float*)(ws + o); o += (size_t)NN*F*4;            // 51.2 MB
    int*   cnt   = (int*)(ws + o);   o += (size_t)NN*4;
    int*   nstart= (int*)(ws + o);   o += (size_t)NN*4;
    int*   ebuf  = (int*)(ws + o);   o += (size_t)NE*4;              // 6.4 MB
    int*   ebuf2 = (int*)(ws + o);   o += (size_t)NE*4;              // 6.4 MB
    float* dinv  = (float*)(ws + o); o += (size_t)NN*4;
    int*   bcnt  = (int*)(ws + o);   o += 1024*4;
    int*   bstart= (int*)(ws + o);   o += 1024*4;
    int*   bcursor=(int*)(ws + o);   o += 1024*4;
    float* z     = (float*)(ws + o); o += (size_t)NG*F*4;
    float* zn    = (float*)(ws + o); o += (size_t)NG*F*4;
    float* qb    = (float*)(ws + o); o += (size_t)NG*F*4;
    float* kb2   = (float*)(ws + o); o += (size_t)NG*F*4;
    float* vb    = (float*)(ws + o); o += (size_t)NG*F*4;
    float* ao    = (float*)(ws + o); o += (size_t)NG*F*4;
    float* ap    = (float*)(ws + o); o += (size_t)NG*F*4;
    float* zd1   = (float*)(ws + o); o += (size_t)NG*F*4;
    float* ffn1  = (float*)(ws + o); o += (size_t)NG*FFN_DIM*4;      // 8.2 MB
    float* ffn2  = (float*)(ws + o); o += (size_t)NG*F*4;
    float* zd2   = (float*)(ws + o); o += (size_t)NG*F*4;
    float* gsi   = (float*)(ws + o); o += (size_t)NG*F*4;

    // ---- GCN phase ----
    hipMemsetAsync(cnt, 0, (size_t)NN*4, stream);
    k_count<<<(NE+255)/256, 256, 0, stream>>>(ei, cnt);
    k_dinv_bcnt<<<(NN+255)/256, 256, 0, stream>>>(cnt, dinv, bcnt);
    k_bscan<<<1, 1024, 0, stream>>>(bcnt, bstart, bcursor);
    k_xws<<<(NN+63)/64, 256, 0, stream>>>(x, W_gcn, dinv, xws);
    k_scatter2<<<SC_BLOCKS, 1024, 0, stream>>>(ei, bcursor, ebuf);
    k_sort<<<NB, 256, 0, stream>>>(ebuf, bstart, cnt, nstart, ebuf2);
    k_agg3<<<NN/4, 256, 0, stream>>>(xws, nstart, cnt, dinv, b_gcn, bn_g, bn_b, ebuf2, h);

    // ---- pool + set transformer (fp32, tiny) ----
    k_pool<<<NG/2, 256, 0, stream>>>(h, z);
    k_ln<<<NG/4, 256, 0, stream>>>(z, nullptr, lnpre_g, lnpre_b, zn);
    dim3 g2(32, 2);
    k_gemm<0><<<g2, 256, 0, stream>>>(zn, Wq, bq, qb, NG, F, F);
    k_gemm<0><<<g2, 256, 0, stream>>>(zn, Wk, bk, kb2, NG, F, F);
    k_gemm<0><<<g2, 256, 0, stream>>>(zn, Wv, bv, vb, NG, F, F);
    k_attn<<<NS*4, 256, 0, stream>>>(qb, kb2, vb, ao);
    k_gemm<0><<<g2, 256, 0, stream>>>(ao, Wo, bo, ap, NG, F, F);
    k_ln<<<NG/4, 256, 0, stream>>>(z, ap, ln1_g, ln1_b, zd1);
    dim3 gffn1(32, 16);
    k_gemm<1><<<gffn1, 256, 0, stream>>>(zd1, W1, b1, ffn1, NG, F, FFN_DIM);
    k_gemm<0><<<g2, 256, 0, stream>>>(ffn1, W2, b2, ffn2, NG, FFN_DIM, F);
    k_ln<<<NG/4, 256, 0, stream>>>(zd1, ffn2, ln2_g, ln2_b, zd2);
    k_gemm<0><<<g2, 256, 0, stream>>>(zd2, Wg + (size_t)F*F, bg, gsi, NG, F, F);

    // ---- gated fusion -> output ----
    dim3 ggate((NN+63)/64, 2);
    k_gate<<<ggate, 256, 0, stream>>>(h, Wg, gsi, zd2, out);
}

// Round 5
// 530.677 us; speedup vs baseline: 3.5405x; 1.1926x over previous
//
#include <hip/hip_runtime.h>
#include <hip/hip_bf16.h>
#include <cstddef>

#define NN 100000
#define NE 1600000
#define NG 2000
#define NS 40
#define INF 64
#define F 128
#define FFN_DIM 1024
#define NB 782            // ceil(100000/128) buckets of 128 nodes
#define SC_BLOCKS 100
#define SC_CHUNK 16000    // 100*16000 = 1.6M edges exactly
#define KSPLIT 8

using bf16 = __hip_bfloat16;
using bf162 = __hip_bfloat162;

// ---------------- degree count ----------------
__global__ __launch_bounds__(256) void k_count(const int* __restrict__ ei, int* __restrict__ cnt){
    int e = blockIdx.x*256 + threadIdx.x;
    if (e < NE) atomicAdd(&cnt[ei[NE + e]], 1);
}

// ---------------- dinv + per-bucket edge counts (fused) ----------------
__global__ __launch_bounds__(256) void k_dinv_bcnt(const int* __restrict__ cnt, float* __restrict__ dinv,
                                                   int* __restrict__ bcnt){
    __shared__ int sd[256];
    int t = threadIdx.x;
    int i = blockIdx.x*256 + t;
    int c = (i < NN) ? cnt[i] : 0;
    if (i < NN) dinv[i] = rsqrtf((float)c + 2.0f);
    sd[t] = c; __syncthreads();
    #pragma unroll
    for (int off=64; off>=1; off>>=1){
        if ((t & 127) < off) sd[t] += sd[t+off];
        __syncthreads();
    }
    if (t == 0)   bcnt[2*blockIdx.x]   = sd[0];
    if (t == 128) bcnt[2*blockIdx.x+1] = sd[128];
}

// ---------------- scan 782 bucket counts -> bstart[783], bcursor ----------------
__global__ __launch_bounds__(1024) void k_bscan(const int* __restrict__ bcnt, int* __restrict__ bstart,
                                                int* __restrict__ bcursor){
    __shared__ int s[1024];
    int t = threadIdx.x;
    int own = (t < NB) ? bcnt[t] : 0;
    s[t] = own; __syncthreads();
    #pragma unroll
    for (int off=1; off<1024; off<<=1){
        int v = (t >= off) ? s[t-off] : 0;
        __syncthreads();
        s[t] += v;
        __syncthreads();
    }
    int excl = s[t] - own;
    if (t <= NB) bstart[t] = excl;     // bstart[782] == NE
    if (t < NB)  bcursor[t] = excl;
}

// ---------------- xws = (x @ W_gcn) * dinv[row], stored bf16 ----------------
__global__ __launch_bounds__(256) void k_xws(const float* __restrict__ x, const float* __restrict__ W,
                                             const float* __restrict__ dinv, bf16* __restrict__ xws){
    __shared__ float As[64*68];    // As[k][r], padded
    __shared__ float Bs[64*128];   // Bs[k][c]
    int t = threadIdx.x;
    int rowBase = blockIdx.x * 64;
    #pragma unroll
    for (int i = 0; i < 32; ++i){ int id = i*256 + t; Bs[id] = W[id]; }
    #pragma unroll
    for (int i = 0; i < 16; ++i){
        int id = i*256 + t; int kk = id & 63; int r = id >> 6;
        int row = rowBase + r;
        As[kk*68 + r] = (row < NN) ? x[(size_t)row*INF + kk] : 0.f;
    }
    __syncthreads();
    int c0 = (t & 31) * 4; int r0 = (t >> 5) * 8;
    float acc[8][4];
    #pragma unroll
    for (int i=0;i<8;i++) { acc[i][0]=0.f; acc[i][1]=0.f; acc[i][2]=0.f; acc[i][3]=0.f; }
    for (int kk = 0; kk < 64; ++kk){
        float4 b = *(const float4*)&Bs[kk*128 + c0];
        float4 a0 = *(const float4*)&As[kk*68 + r0];
        float4 a1 = *(const float4*)&As[kk*68 + r0 + 4];
        float av[8] = {a0.x,a0.y,a0.z,a0.w,a1.x,a1.y,a1.z,a1.w};
        #pragma unroll
        for (int i=0;i<8;i++){
            acc[i][0] += av[i]*b.x; acc[i][1] += av[i]*b.y;
            acc[i][2] += av[i]*b.z; acc[i][3] += av[i]*b.w;
        }
    }
    for (int i=0;i<8;i++){
        int row = rowBase + r0 + i;
        if (row < NN){
            float dv = dinv[row];
            for (int j=0;j<4;j++)
                xws[(size_t)row*F + c0 + j] = __float2bfloat16(acc[i][j]*dv);
        }
    }
}

// ---------------- binned scatter: pack (row<<7|col&127) into bucket regions ----------------
__global__ __launch_bounds__(1024) void k_scatter2(const int* __restrict__ ei, int* __restrict__ bcursor,
                                                   int* __restrict__ ebuf){
    __shared__ int lh[NB];
    __shared__ int lb[NB];
    int t = threadIdx.x;
    int base = blockIdx.x * SC_CHUNK;
    for (int b=t; b<NB; b+=1024) lh[b] = 0;
    __syncthreads();
    // pass 1: local histogram
    for (int i=t; i<SC_CHUNK; i+=1024){
        int c = ei[NE + base + i];
        atomicAdd(&lh[c>>7], 1);
    }
    __syncthreads();
    // reserve global runs
    for (int b=t; b<NB; b+=1024){
        int n = lh[b];
        lb[b] = n ? atomicAdd(&bcursor[b], n) : 0;
        lh[b] = 0;
    }
    __syncthreads();
    // pass 2: place
    for (int i=t; i<SC_CHUNK; i+=1024){
        int r = ei[base + i];
        int c = ei[NE + base + i];
        int b = c >> 7;
        int rk = atomicAdd(&lh[b], 1);
        ebuf[lb[b] + rk] = (r << 7) | (c & 127);
    }
}

// ---------------- per-bucket counting sort -> node-sorted rows + per-node CSR starts ----------------
__global__ __launch_bounds__(256) void k_sort(const int* __restrict__ ebuf, const int* __restrict__ bstart,
                                              const int* __restrict__ cnt, int* __restrict__ nstart,
                                              int* __restrict__ ebuf2){
    __shared__ int s[128];
    __shared__ int lcur[128];
    int t = threadIdx.x;
    int b = blockIdx.x;
    int n0 = b * 128;
    int node = n0 + t;
    int c = 0;
    if (t < 128) c = (node < NN) ? cnt[node] : 0;
    if (t < 128) s[t] = c;
    __syncthreads();
    #pragma unroll
    for (int off=1; off<128; off<<=1){
        int v = (t >= off && t < 128) ? s[t-off] : 0;
        __syncthreads();
        if (t < 128) s[t] += v;
        __syncthreads();
    }
    int e0 = bstart[b];
    if (t < 128){
        int excl = s[t] - c;
        lcur[t] = excl;
        if (node < NN) nstart[node] = e0 + excl;
    }
    __syncthreads();
    int nE = bstart[b+1] - e0;
    for (int i=t; i<nE; i+=256){
        int v = ebuf[e0 + i];
        int nl = v & 127;
        int rk = atomicAdd(&lcur[nl], 1);
        ebuf2[e0 + rk] = v >> 7;     // row index
    }
}

// ---------------- per-node CSR gather + GCN epilogue + BN + ReLU -> h (fp32) ----------------
__global__ __launch_bounds__(256) void k_agg3(const bf16* __restrict__ xws, const int* __restrict__ nstart,
                                              const int* __restrict__ cnt, const float* __restrict__ dinv,
                                              const float* __restrict__ b_gcn, const float* __restrict__ bn_g,
                                              const float* __restrict__ bn_b, const int* __restrict__ ebuf2,
                                              float* __restrict__ h){
    int t = threadIdx.x; int lane = t & 63;
    int node = blockIdx.x*4 + (t>>6);
    int s0 = nstart[node]; int dg = cnt[node]; float dv = dinv[node];
    const bf162* xw2 = (const bf162*)xws;
    float a0=0.f, a1=0.f;
    int j=0;
    for (; j+4<=dg; j+=4){
        int r0 = ebuf2[s0+j], r1 = ebuf2[s0+j+1], r2 = ebuf2[s0+j+2], r3 = ebuf2[s0+j+3];
        float2 f0 = __bfloat1622float2(xw2[(size_t)r0*64 + lane]);
        float2 f1 = __bfloat1622float2(xw2[(size_t)r1*64 + lane]);
        float2 f2 = __bfloat1622float2(xw2[(size_t)r2*64 + lane]);
        float2 f3 = __bfloat1622float2(xw2[(size_t)r3*64 + lane]);
        a0 += (f0.x + f1.x) + (f2.x + f3.x);
        a1 += (f0.y + f1.y) + (f2.y + f3.y);
    }
    for (; j<dg; ++j){
        int r0 = ebuf2[s0+j];
        float2 f0 = __bfloat1622float2(xw2[(size_t)r0*64 + lane]);
        a0 += f0.x; a1 += f0.y;
    }
    float2 fs = __bfloat1622float2(xw2[(size_t)node*64 + lane]);
    float p0 = dv*(a0 + 2.f*fs.x) + b_gcn[2*lane];
    float p1 = dv*(a1 + 2.f*fs.y) + b_gcn[2*lane+1];
    float bns = rsqrtf(1.f + 1e-5f);
    p0 = p0*bns*bn_g[2*lane]   + bn_b[2*lane];
    p1 = p1*bns*bn_g[2*lane+1] + bn_b[2*lane+1];
    h[(size_t)node*F + 2*lane]   = fmaxf(p0, 0.f);
    h[(size_t)node*F + 2*lane+1] = fmaxf(p1, 0.f);
}

// ---------------- mean pool (50 nodes/graph) ----------------
__global__ __launch_bounds__(256) void k_pool(const float* __restrict__ h, float* __restrict__ z){
    int t = threadIdx.x;
    int g = blockIdx.x*2 + (t>>7);
    int f = t & 127;
    float s = 0.f;
    const float* p = h + (size_t)g*50*F + f;
    #pragma unroll 5
    for (int i=0;i<50;i++) s += p[i*F];
    z[g*F+f] = s / 50.0f;
}

// ---------------- LayerNorm (optional residual add) ----------------
__global__ __launch_bounds__(256) void k_ln(const float* __restrict__ A, const float* __restrict__ R,
                                            const float* __restrict__ g, const float* __restrict__ b,
                                            float* __restrict__ out){
    int t = threadIdx.x; int lane = t&63;
    int row = blockIdx.x*4 + (t>>6);
    int i0 = row*F + 2*lane;
    float x0 = A[i0], x1 = A[i0+1];
    if (R){ x0 += R[i0]; x1 += R[i0+1]; }
    float s = x0+x1;
    for (int off=1; off<64; off<<=1) s += __shfl_xor(s, off);
    float m = s * (1.f/128.f);
    float d0 = x0-m, d1 = x1-m;
    float vv = d0*d0 + d1*d1;
    for (int off=1; off<64; off<<=1) vv += __shfl_xor(vv, off);
    float rs = rsqrtf(vv*(1.f/128.f) + 1e-5f);
    out[i0]   = d0*rs*g[2*lane]   + b[2*lane];
    out[i0+1] = d1*rs*g[2*lane+1] + b[2*lane+1];
}

// ---------------- LN over (A + sum of KSPLIT partials + bias) ----------------
__global__ __launch_bounds__(256) void k_ln_red(const float* __restrict__ A, const float* __restrict__ part,
                                                const float* __restrict__ bias, const float* __restrict__ g,
                                                const float* __restrict__ b, float* __restrict__ out){
    int t = threadIdx.x; int lane = t&63;
    int row = blockIdx.x*4 + (t>>6);
    int i0 = row*F + 2*lane;
    float x0 = A[i0] + bias[2*lane], x1 = A[i0+1] + bias[2*lane+1];
    #pragma unroll
    for (int zz=0; zz<KSPLIT; ++zz){
        x0 += part[(size_t)zz*NG*F + i0];
        x1 += part[(size_t)zz*NG*F + i0 + 1];
    }
    float s = x0+x1;
    for (int off=1; off<64; off<<=1) s += __shfl_xor(s, off);
    float m = s * (1.f/128.f);
    float d0 = x0-m, d1 = x1-m;
    float vv = d0*d0 + d1*d1;
    for (int off=1; off<64; off<<=1) vv += __shfl_xor(vv, off);
    float rs = rsqrtf(vv*(1.f/128.f) + 1e-5f);
    out[i0]   = d0*rs*g[2*lane]   + b[2*lane];
    out[i0+1] = d1*rs*g[2*lane+1] + b[2*lane+1];
}

// ---------------- generic small GEMM: C = A[MxK] @ B[KxN] + bias, opt ReLU ----------------
template<int RELU>
__global__ __launch_bounds__(256) void k_gemm(const float* __restrict__ A, const float* __restrict__ B,
                                              const float* __restrict__ bias, float* __restrict__ C,
                                              int M, int K, int Nc){
    __shared__ float As[32*68];
    __shared__ float Bs[32*64];
    int t = threadIdx.x;
    int rowBase = blockIdx.x*64;
    int colBase = blockIdx.y*64;
    int c0 = (t&15)*4, r0 = (t>>4)*4;
    float acc[4][4];
    #pragma unroll
    for (int i=0;i<4;i++){ acc[i][0]=0.f; acc[i][1]=0.f; acc[i][2]=0.f; acc[i][3]=0.f; }
    for (int kb=0; kb<K; kb+=32){
        #pragma unroll
        for (int i=0;i<8;i++){
            int id = i*256+t; int kk = id&31; int r = id>>5;
            int row = rowBase + r;
            As[kk*68+r] = (row<M) ? A[(size_t)row*K + kb + kk] : 0.f;
        }
        #pragma unroll
        for (int i=0;i<8;i++){
            int id = i*256+t; int c = id&63; int kk = id>>6;
            Bs[kk*64+c] = B[(size_t)(kb+kk)*Nc + colBase + c];
        }
        __syncthreads();
        for (int kk=0;kk<32;kk++){
            float4 a = *(const float4*)&As[kk*68+r0];
            float4 b = *(const float4*)&Bs[kk*64+c0];
            float av[4]={a.x,a.y,a.z,a.w}; float bv[4]={b.x,b.y,b.z,b.w};
            #pragma unroll
            for(int i=0;i<4;i++)
                #pragma unroll
                for(int j=0;j<4;j++) acc[i][j] += av[i]*bv[j];
        }
        __syncthreads();
    }
    for (int i=0;i<4;i++){
        int row = rowBase + r0 + i;
        if (row < M){
            for (int j=0;j<4;j++){
                float v = acc[i][j] + bias[colBase+c0+j];
                if (RELU) v = fmaxf(v, 0.f);
                C[(size_t)row*Nc + colBase + c0 + j] = v;
            }
        }
    }
}

// ---------------- split-K GEMM: part[z] = A[:, zK:(z+1)K] @ B[zK:(z+1)K, :] (no bias) ----------------
__global__ __launch_bounds__(256) void k_gemm_splitk(const float* __restrict__ A, const float* __restrict__ B,
                                                     float* __restrict__ part, int M, int K, int Nc){
    __shared__ float As[32*68];
    __shared__ float Bs[32*64];
    int t = threadIdx.x;
    int rowBase = blockIdx.x*64;
    int colBase = blockIdx.y*64;
    int z = blockIdx.z;
    int kchunk = K / KSPLIT;
    int kbeg = z * kchunk;
    int c0 = (t&15)*4, r0 = (t>>4)*4;
    float acc[4][4];
    #pragma unroll
    for (int i=0;i<4;i++){ acc[i][0]=0.f; acc[i][1]=0.f; acc[i][2]=0.f; acc[i][3]=0.f; }
    for (int kb=kbeg; kb<kbeg+kchunk; kb+=32){
        #pragma unroll
        for (int i=0;i<8;i++){
            int id = i*256+t; int kk = id&31; int r = id>>5;
            int row = rowBase + r;
            As[kk*68+r] = (row<M) ? A[(size_t)row*K + kb + kk] : 0.f;
        }
        #pragma unroll
        for (int i=0;i<8;i++){
            int id = i*256+t; int c = id&63; int kk = id>>6;
            Bs[kk*64+c] = B[(size_t)(kb+kk)*Nc + colBase + c];
        }
        __syncthreads();
        for (int kk=0;kk<32;kk++){
            float4 a = *(const float4*)&As[kk*68+r0];
            float4 b = *(const float4*)&Bs[kk*64+c0];
            float av[4]={a.x,a.y,a.z,a.w}; float bv[4]={b.x,b.y,b.z,b.w};
            #pragma unroll
            for(int i=0;i<4;i++)
                #pragma unroll
                for(int j=0;j<4;j++) acc[i][j] += av[i]*bv[j];
        }
        __syncthreads();
    }
    float* Cp = part + (size_t)z*M*Nc;
    for (int i=0;i<4;i++){
        int row = rowBase + r0 + i;
        if (row < M){
            for (int j=0;j<4;j++)
                Cp[(size_t)row*Nc + colBase + c0 + j] = acc[i][j];
        }
    }
}

// ---------------- fused QKV projections (A shared; blockIdx.z selects weights) ----------------
__global__ __launch_bounds__(256) void k_gemm_qkv(const float* __restrict__ A,
                                                  const float* __restrict__ Wq, const float* __restrict__ Wk,
                                                  const float* __restrict__ Wv, const float* __restrict__ bq,
                                                  const float* __restrict__ bk, const float* __restrict__ bv,
                                                  float* __restrict__ Cq, float* __restrict__ Ck,
                                                  float* __restrict__ Cv){
    __shared__ float As[32*68];
    __shared__ float Bs[32*64];
    int t = threadIdx.x;
    int rowBase = blockIdx.x*64;
    int colBase = blockIdx.y*64;
    int z = blockIdx.z;
    const float* B = (z==0) ? Wq : (z==1) ? Wk : Wv;
    const float* bias = (z==0) ? bq : (z==1) ? bk : bv;
    float* C = (z==0) ? Cq : (z==1) ? Ck : Cv;
    int c0 = (t&15)*4, r0 = (t>>4)*4;
    float acc[4][4];
    #pragma unroll
    for (int i=0;i<4;i++){ acc[i][0]=0.f; acc[i][1]=0.f; acc[i][2]=0.f; acc[i][3]=0.f; }
    for (int kb=0; kb<F; kb+=32){
        #pragma unroll
        for (int i=0;i<8;i++){
            int id = i*256+t; int kk = id&31; int r = id>>5;
            int row = rowBase + r;
            As[kk*68+r] = (row<NG) ? A[(size_t)row*F + kb + kk] : 0.f;
        }
        #pragma unroll
        for (int i=0;i<8;i++){
            int id = i*256+t; int c = id&63; int kk = id>>6;
            Bs[kk*64+c] = B[(size_t)(kb+kk)*F + colBase + c];
        }
        __syncthreads();
        for (int kk=0;kk<32;kk++){
            float4 a = *(const float4*)&As[kk*68+r0];
            float4 b = *(const float4*)&Bs[kk*64+c0];
            float av[4]={a.x,a.y,a.z,a.w}; float bv4[4]={b.x,b.y,b.z,b.w};
            #pragma unroll
            for(int i=0;i<4;i++)
                #pragma unroll
                for(int j=0;j<4;j++) acc[i][j] += av[i]*bv4[j];
        }
        __syncthreads();
    }
    for (int i=0;i<4;i++){
        int row = rowBase + r0 + i;
        if (row < NG){
            for (int j=0;j<4;j++)
                C[(size_t)row*F + colBase + c0 + j] = acc[i][j] + bias[colBase+c0+j];
        }
    }
}

// ---------------- attention: one block per (set, head) ----------------
__global__ __launch_bounds__(256) void k_attn(const float* __restrict__ q, const float* __restrict__ k,
                                              const float* __restrict__ v, float* __restrict__ o){
    __shared__ float Qs[1600], Ks[1600], Vs[1600], Sc[2500];
    int t = threadIdx.x;
    int s = blockIdx.x >> 2; int hh = blockIdx.x & 3;
    for (int idx=t; idx<1600; idx+=256){
        int i = idx>>5, d = idx&31;
        size_t gi = (size_t)(s*50+i)*F + hh*32 + d;
        Qs[idx]=q[gi]; Ks[idx]=k[gi]; Vs[idx]=v[gi];
    }
    __syncthreads();
    for (int idx=t; idx<2500; idx+=256){
        int qi = idx/50, ki = idx%50;
        float acc=0.f;
        #pragma unroll 8
        for (int d=0;d<32;d++) acc += Qs[qi*32+d]*Ks[ki*32+d];
        Sc[idx] = acc * 0.17677669529663687f;   // 1/sqrt(32)
    }
    __syncthreads();
    if (t < 50){
        float m=-1e30f;
        for (int j=0;j<50;j++) m = fmaxf(m, Sc[t*50+j]);
        float sum=0.f;
        for (int j=0;j<50;j++){ float e=__expf(Sc[t*50+j]-m); Sc[t*50+j]=e; sum+=e; }
        float inv = 1.f/sum;
        for (int j=0;j<50;j++) Sc[t*50+j] *= inv;
    }
    __syncthreads();
    for (int idx=t; idx<1600; idx+=256){
        int qi = idx>>5, d = idx&31;
        float acc=0.f;
        #pragma unroll 10
        for (int ki=0;ki<50;ki++) acc += Sc[qi*50+ki]*Vs[ki*32+d];
        o[(size_t)(s*50+qi)*F + hh*32 + d] = acc;
    }
}

// ---------------- gate GEMM (h @ Wg_top) + sigmoid blend epilogue -> out fp32 ----------------
__global__ __launch_bounds__(256) void k_gate(const float* __restrict__ h, const float* __restrict__ Wg,
                                              const float* __restrict__ gsi, const float* __restrict__ zd2,
                                              float* __restrict__ out){
    __shared__ float As[32*68];
    __shared__ float Bs[32*64];
    int t = threadIdx.x;
    int rowBase = blockIdx.x*64;
    int colBase = blockIdx.y*64;
    int c0=(t&15)*4, r0=(t>>4)*4;
    float acc[4][4];
    #pragma unroll
    for (int i=0;i<4;i++){ acc[i][0]=0.f; acc[i][1]=0.f; acc[i][2]=0.f; acc[i][3]=0.f; }
    for (int kb=0; kb<F; kb+=32){
        #pragma unroll
        for (int i=0;i<8;i++){
            int id=i*256+t; int kk=id&31; int r=id>>5;
            int row=rowBase+r;
            As[kk*68+r]=(row<NN)?h[(size_t)row*F+kb+kk]:0.f;
        }
        #pragma unroll
        for (int i=0;i<8;i++){
            int id=i*256+t; int c=id&63; int kk=id>>6;
            Bs[kk*64+c]=Wg[(size_t)(kb+kk)*F + colBase + c];  // top 128 rows of Wg
        }
        __syncthreads();
        for (int kk=0;kk<32;kk++){
            float4 a=*(const float4*)&As[kk*68+r0];
            float4 b=*(const float4*)&Bs[kk*64+c0];
            float av[4]={a.x,a.y,a.z,a.w}, bv[4]={b.x,b.y,b.z,b.w};
            #pragma unroll
            for(int i=0;i<4;i++)
                #pragma unroll
                for(int j=0;j<4;j++) acc[i][j]+=av[i]*bv[j];
        }
        __syncthreads();
    }
    for (int i=0;i<4;i++){
        int row=rowBase+r0+i;
        if (row<NN){
            int g = row/50;
            for (int j=0;j<4;j++){
                int col = colBase+c0+j;
                float L = acc[i][j] + gsi[g*F+col];
                float gate = 1.f/(1.f+__expf(-L));
                float si = zd2[g*F+col];
                float hv = h[(size_t)row*F+col];
                out[(size_t)row*F+col] = gate*si + (1.f-gate)*hv;
            }
        }
    }
}

extern "C" void kernel_launch(void* const* d_in, const int* in_sizes, int n_in,
                              void* d_out, int out_size, void* d_ws, size_t ws_size,
                              hipStream_t stream) {
    const float* x      = (const float*)d_in[0];
    const int*   ei     = (const int*)d_in[1];
    const float* W_gcn  = (const float*)d_in[4];
    const float* b_gcn  = (const float*)d_in[5];
    const float* bn_g   = (const float*)d_in[6];
    const float* bn_b   = (const float*)d_in[7];
    const float* lnpre_g= (const float*)d_in[8];
    const float* lnpre_b= (const float*)d_in[9];
    const float* Wq     = (const float*)d_in[10];
    const float* bq     = (const float*)d_in[11];
    const float* Wk     = (const float*)d_in[12];
    const float* bk     = (const float*)d_in[13];
    const float* Wv     = (const float*)d_in[14];
    const float* bv     = (const float*)d_in[15];
    const float* Wo     = (const float*)d_in[16];
    const float* bo     = (const float*)d_in[17];
    const float* ln1_g  = (const float*)d_in[18];
    const float* ln1_b  = (const float*)d_in[19];
    const float* W1     = (const float*)d_in[20];
    const float* b1     = (const float*)d_in[21];
    const float* W2     = (const float*)d_in[22];
    const float* b2     = (const float*)d_in[23];
    const float* ln2_g  = (const float*)d_in[24];
    const float* ln2_b  = (const float*)d_in[25];
    const float* Wg     = (const float*)d_in[26];
    const float* bg     = (const float*)d_in[27];
    float* out = (float*)d_out;
    char* ws = (char*)d_ws;

    // workspace layout
    size_t o = 0;
    bf16*  xws   = (bf16*)(ws + o);  o += (size_t)NN*F*2;            // 25.6 MB
    float* h     = (float*)(ws + o); o += (size_t)NN*F*4;            // 51.2 MB
    int*   cnt   = (int*)(ws + o);   o += (size_t)NN*4;
    int*   nstart= (int*)(ws + o);   o += (size_t)NN*4;
    int*   ebuf  = (int*)(ws + o);   o += (size_t)NE*4;              // 6.4 MB
    int*   ebuf2 = (int*)(ws + o);   o += (size_t)NE*4;              // 6.4 MB
    float* dinv  = (float*)(ws + o); o += (size_t)NN*4;
    int*   bcnt  = (int*)(ws + o);   o += 1024*4;
    int*   bstart= (int*)(ws + o);   o += 1024*4;
    int*   bcursor=(int*)(ws + o);   o += 1024*4;
    float* z     = (float*)(ws + o); o += (size_t)NG*F*4;
    float* zn    = (float*)(ws + o); o += (size_t)NG*F*4;
    float* qb    = (float*)(ws + o); o += (size_t)NG*F*4;
    float* kb2   = (float*)(ws + o); o += (size_t)NG*F*4;
    float* vb    = (float*)(ws + o); o += (size_t)NG*F*4;
    float* ao    = (float*)(ws + o); o += (size_t)NG*F*4;
    float* ap    = (float*)(ws + o); o += (size_t)NG*F*4;
    float* zd1   = (float*)(ws + o); o += (size_t)NG*F*4;
    float* ffn1  = (float*)(ws + o); o += (size_t)NG*FFN_DIM*4;      // 8.2 MB
    float* part  = (float*)(ws + o); o += (size_t)KSPLIT*NG*F*4;     // 8.2 MB
    float* zd2   = (float*)(ws + o); o += (size_t)NG*F*4;
    float* gsi   = (float*)(ws + o); o += (size_t)NG*F*4;

    // ---- GCN phase ----
    hipMemsetAsync(cnt, 0, (size_t)NN*4, stream);
    k_count<<<(NE+255)/256, 256, 0, stream>>>(ei, cnt);
    k_dinv_bcnt<<<(NN+255)/256, 256, 0, stream>>>(cnt, dinv, bcnt);
    k_bscan<<<1, 1024, 0, stream>>>(bcnt, bstart, bcursor);
    k_xws<<<(NN+63)/64, 256, 0, stream>>>(x, W_gcn, dinv, xws);
    k_scatter2<<<SC_BLOCKS, 1024, 0, stream>>>(ei, bcursor, ebuf);
    k_sort<<<NB, 256, 0, stream>>>(ebuf, bstart, cnt, nstart, ebuf2);
    k_agg3<<<NN/4, 256, 0, stream>>>(xws, nstart, cnt, dinv, b_gcn, bn_g, bn_b, ebuf2, h);

    // ---- pool + set transformer (fp32, tiny) ----
    k_pool<<<NG/2, 256, 0, stream>>>(h, z);
    k_ln<<<NG/4, 256, 0, stream>>>(z, nullptr, lnpre_g, lnpre_b, zn);
    dim3 gqkv(32, 2, 3);
    k_gemm_qkv<<<gqkv, 256, 0, stream>>>(zn, Wq, Wk, Wv, bq, bk, bv, qb, kb2, vb);
    k_attn<<<NS*4, 256, 0, stream>>>(qb, kb2, vb, ao);
    dim3 g2(32, 2);
    k_gemm<0><<<g2, 256, 0, stream>>>(ao, Wo, bo, ap, NG, F, F);
    k_ln<<<NG/4, 256, 0, stream>>>(z, ap, ln1_g, ln1_b, zd1);
    dim3 gffn1(32, 16);
    k_gemm<1><<<gffn1, 256, 0, stream>>>(zd1, W1, b1, ffn1, NG, F, FFN_DIM);
    dim3 gsk(32, 2, KSPLIT);
    k_gemm_splitk<<<gsk, 256, 0, stream>>>(ffn1, W2, part, NG, FFN_DIM, F);
    k_ln_red<<<NG/4, 256, 0, stream>>>(zd1, part, b2, ln2_g, ln2_b, zd2);
    k_gemm<0><<<g2, 256, 0, stream>>>(zd2, Wg + (size_t)F*F, bg, gsi, NG, F, F);

    // ---- gated fusion -> output ----
    dim3 ggate((NN+63)/64, 2);
    k_gate<<<ggate, 256, 0, stream>>>(h, Wg, gsi, zd2, out);
}

// Round 6
// 504.903 us; speedup vs baseline: 3.7213x; 1.0510x over previous
//
#include <hip/hip_runtime.h>
#include <hip/hip_bf16.h>
#include <cstddef>

#define NN 100000
#define NE 1600000
#define NG 2000
#define NS 40
#define INF 64
#define F 128
#define FFN_DIM 1024
#define NB 782            // ceil(100000/128) buckets of 128 nodes
#define SC_BLOCKS 100
#define SC_CHUNK 16000    // 100*16000 = 1.6M edges exactly
#define KSPLIT 8

using bf16 = __hip_bfloat16;
using bf162 = __hip_bfloat162;
typedef __attribute__((ext_vector_type(8))) short short8;
typedef __attribute__((ext_vector_type(4))) float f32x4;

__device__ __forceinline__ short f2bs(float f){
    union { bf16 b; short s; } u; u.b = __float2bfloat16(f); return u.s;
}

// ---------------- degree count ----------------
__global__ __launch_bounds__(256) void k_count(const int* __restrict__ ei, int* __restrict__ cnt){
    int e = blockIdx.x*256 + threadIdx.x;
    if (e < NE) atomicAdd(&cnt[ei[NE + e]], 1);
}

// ---------------- dinv + per-bucket edge counts (fused) ----------------
__global__ __launch_bounds__(256) void k_dinv_bcnt(const int* __restrict__ cnt, float* __restrict__ dinv,
                                                   int* __restrict__ bcnt){
    __shared__ int sd[256];
    int t = threadIdx.x;
    int i = blockIdx.x*256 + t;
    int c = (i < NN) ? cnt[i] : 0;
    if (i < NN) dinv[i] = rsqrtf((float)c + 2.0f);
    sd[t] = c; __syncthreads();
    #pragma unroll
    for (int off=64; off>=1; off>>=1){
        if ((t & 127) < off) sd[t] += sd[t+off];
        __syncthreads();
    }
    if (t == 0)   bcnt[2*blockIdx.x]   = sd[0];
    if (t == 128) bcnt[2*blockIdx.x+1] = sd[128];
}

// ---------------- scan 782 bucket counts -> bstart[783], bcursor ----------------
__global__ __launch_bounds__(1024) void k_bscan(const int* __restrict__ bcnt, int* __restrict__ bstart,
                                                int* __restrict__ bcursor){
    __shared__ int s[1024];
    int t = threadIdx.x;
    int own = (t < NB) ? bcnt[t] : 0;
    s[t] = own; __syncthreads();
    #pragma unroll
    for (int off=1; off<1024; off<<=1){
        int v = (t >= off) ? s[t-off] : 0;
        __syncthreads();
        s[t] += v;
        __syncthreads();
    }
    int excl = s[t] - own;
    if (t <= NB) bstart[t] = excl;     // bstart[782] == NE
    if (t < NB)  bcursor[t] = excl;
}

// ---------------- xws = (x @ W_gcn) * dinv[row], stored bf16 ----------------
__global__ __launch_bounds__(256) void k_xws(const float* __restrict__ x, const float* __restrict__ W,
                                             const float* __restrict__ dinv, bf16* __restrict__ xws){
    __shared__ float As[64*68];    // As[k][r], padded
    __shared__ float Bs[64*128];   // Bs[k][c]
    int t = threadIdx.x;
    int rowBase = blockIdx.x * 64;
    #pragma unroll
    for (int i = 0; i < 32; ++i){ int id = i*256 + t; Bs[id] = W[id]; }
    #pragma unroll
    for (int i = 0; i < 16; ++i){
        int id = i*256 + t; int kk = id & 63; int r = id >> 6;
        int row = rowBase + r;
        As[kk*68 + r] = (row < NN) ? x[(size_t)row*INF + kk] : 0.f;
    }
    __syncthreads();
    int c0 = (t & 31) * 4; int r0 = (t >> 5) * 8;
    float acc[8][4];
    #pragma unroll
    for (int i=0;i<8;i++) { acc[i][0]=0.f; acc[i][1]=0.f; acc[i][2]=0.f; acc[i][3]=0.f; }
    for (int kk = 0; kk < 64; ++kk){
        float4 b = *(const float4*)&Bs[kk*128 + c0];
        float4 a0 = *(const float4*)&As[kk*68 + r0];
        float4 a1 = *(const float4*)&As[kk*68 + r0 + 4];
        float av[8] = {a0.x,a0.y,a0.z,a0.w,a1.x,a1.y,a1.z,a1.w};
        #pragma unroll
        for (int i=0;i<8;i++){
            acc[i][0] += av[i]*b.x; acc[i][1] += av[i]*b.y;
            acc[i][2] += av[i]*b.z; acc[i][3] += av[i]*b.w;
        }
    }
    for (int i=0;i<8;i++){
        int row = rowBase + r0 + i;
        if (row < NN){
            float dv = dinv[row];
            for (int j=0;j<4;j++)
                xws[(size_t)row*F + c0 + j] = __float2bfloat16(acc[i][j]*dv);
        }
    }
}

// ---------------- binned scatter: pack (row<<7|col&127) into bucket regions ----------------
__global__ __launch_bounds__(1024) void k_scatter2(const int* __restrict__ ei, int* __restrict__ bcursor,
                                                   int* __restrict__ ebuf){
    __shared__ int lh[NB];
    __shared__ int lb[NB];
    int t = threadIdx.x;
    int base = blockIdx.x * SC_CHUNK;
    for (int b=t; b<NB; b+=1024) lh[b] = 0;
    __syncthreads();
    // pass 1: local histogram
    for (int i=t; i<SC_CHUNK; i+=1024){
        int c = ei[NE + base + i];
        atomicAdd(&lh[c>>7], 1);
    }
    __syncthreads();
    // reserve global runs
    for (int b=t; b<NB; b+=1024){
        int n = lh[b];
        lb[b] = n ? atomicAdd(&bcursor[b], n) : 0;
        lh[b] = 0;
    }
    __syncthreads();
    // pass 2: place
    for (int i=t; i<SC_CHUNK; i+=1024){
        int r = ei[base + i];
        int c = ei[NE + base + i];
        int b = c >> 7;
        int rk = atomicAdd(&lh[b], 1);
        ebuf[lb[b] + rk] = (r << 7) | (c & 127);
    }
}

// ---------------- per-bucket counting sort -> node-sorted rows + per-node CSR starts ----------------
__global__ __launch_bounds__(256) void k_sort(const int* __restrict__ ebuf, const int* __restrict__ bstart,
                                              const int* __restrict__ cnt, int* __restrict__ nstart,
                                              int* __restrict__ ebuf2){
    __shared__ int s[128];
    __shared__ int lcur[128];
    int t = threadIdx.x;
    int b = blockIdx.x;
    int n0 = b * 128;
    int node = n0 + t;
    int c = 0;
    if (t < 128) c = (node < NN) ? cnt[node] : 0;
    if (t < 128) s[t] = c;
    __syncthreads();
    #pragma unroll
    for (int off=1; off<128; off<<=1){
        int v = (t >= off && t < 128) ? s[t-off] : 0;
        __syncthreads();
        if (t < 128) s[t] += v;
        __syncthreads();
    }
    int e0 = bstart[b];
    if (t < 128){
        int excl = s[t] - c;
        lcur[t] = excl;
        if (node < NN) nstart[node] = e0 + excl;
    }
    __syncthreads();
    int nE = bstart[b+1] - e0;
    for (int i=t; i<nE; i+=256){
        int v = ebuf[e0 + i];
        int nl = v & 127;
        int rk = atomicAdd(&lcur[nl], 1);
        ebuf2[e0 + rk] = v >> 7;     // row index
    }
}

// ---------------- per-node CSR gather + GCN epilogue + BN + ReLU -> h (fp32) ----------------
__global__ __launch_bounds__(256) void k_agg3(const bf16* __restrict__ xws, const int* __restrict__ nstart,
                                              const int* __restrict__ cnt, const float* __restrict__ dinv,
                                              const float* __restrict__ b_gcn, const float* __restrict__ bn_g,
                                              const float* __restrict__ bn_b, const int* __restrict__ ebuf2,
                                              float* __restrict__ h){
    int t = threadIdx.x; int lane = t & 63;
    int node = blockIdx.x*4 + (t>>6);
    int s0 = nstart[node]; int dg = cnt[node]; float dv = dinv[node];
    const bf162* xw2 = (const bf162*)xws;
    float a0=0.f, a1=0.f;
    int j=0;
    for (; j+4<=dg; j+=4){
        int r0 = ebuf2[s0+j], r1 = ebuf2[s0+j+1], r2 = ebuf2[s0+j+2], r3 = ebuf2[s0+j+3];
        float2 f0 = __bfloat1622float2(xw2[(size_t)r0*64 + lane]);
        float2 f1 = __bfloat1622float2(xw2[(size_t)r1*64 + lane]);
        float2 f2 = __bfloat1622float2(xw2[(size_t)r2*64 + lane]);
        float2 f3 = __bfloat1622float2(xw2[(size_t)r3*64 + lane]);
        a0 += (f0.x + f1.x) + (f2.x + f3.x);
        a1 += (f0.y + f1.y) + (f2.y + f3.y);
    }
    for (; j<dg; ++j){
        int r0 = ebuf2[s0+j];
        float2 f0 = __bfloat1622float2(xw2[(size_t)r0*64 + lane]);
        a0 += f0.x; a1 += f0.y;
    }
    float2 fs = __bfloat1622float2(xw2[(size_t)node*64 + lane]);
    float p0 = dv*(a0 + 2.f*fs.x) + b_gcn[2*lane];
    float p1 = dv*(a1 + 2.f*fs.y) + b_gcn[2*lane+1];
    float bns = rsqrtf(1.f + 1e-5f);
    p0 = p0*bns*bn_g[2*lane]   + bn_b[2*lane];
    p1 = p1*bns*bn_g[2*lane+1] + bn_b[2*lane+1];
    h[(size_t)node*F + 2*lane]   = fmaxf(p0, 0.f);
    h[(size_t)node*F + 2*lane+1] = fmaxf(p1, 0.f);
}

// ---------------- mean pool (50 nodes/graph) ----------------
__global__ __launch_bounds__(256) void k_pool(const float* __restrict__ h, float* __restrict__ z){
    int t = threadIdx.x;
    int g = blockIdx.x*2 + (t>>7);
    int f = t & 127;
    float s = 0.f;
    const float* p = h + (size_t)g*50*F + f;
    #pragma unroll 5
    for (int i=0;i<50;i++) s += p[i*F];
    z[g*F+f] = s / 50.0f;
}

// ---------------- LayerNorm (optional residual add) ----------------
__global__ __launch_bounds__(256) void k_ln(const float* __restrict__ A, const float* __restrict__ R,
                                            const float* __restrict__ g, const float* __restrict__ b,
                                            float* __restrict__ out){
    int t = threadIdx.x; int lane = t&63;
    int row = blockIdx.x*4 + (t>>6);
    int i0 = row*F + 2*lane;
    float x0 = A[i0], x1 = A[i0+1];
    if (R){ x0 += R[i0]; x1 += R[i0+1]; }
    float s = x0+x1;
    for (int off=1; off<64; off<<=1) s += __shfl_xor(s, off);
    float m = s * (1.f/128.f);
    float d0 = x0-m, d1 = x1-m;
    float vv = d0*d0 + d1*d1;
    for (int off=1; off<64; off<<=1) vv += __shfl_xor(vv, off);
    float rs = rsqrtf(vv*(1.f/128.f) + 1e-5f);
    out[i0]   = d0*rs*g[2*lane]   + b[2*lane];
    out[i0+1] = d1*rs*g[2*lane+1] + b[2*lane+1];
}

// ---------------- LN over (A + sum of KSPLIT partials + bias) ----------------
__global__ __launch_bounds__(256) void k_ln_red(const float* __restrict__ A, const float* __restrict__ part,
                                                const float* __restrict__ bias, const float* __restrict__ g,
                                                const float* __restrict__ b, float* __restrict__ out){
    int t = threadIdx.x; int lane = t&63;
    int row = blockIdx.x*4 + (t>>6);
    int i0 = row*F + 2*lane;
    float x0 = A[i0] + bias[2*lane], x1 = A[i0+1] + bias[2*lane+1];
    #pragma unroll
    for (int zz=0; zz<KSPLIT; ++zz){
        x0 += part[(size_t)zz*NG*F + i0];
        x1 += part[(size_t)zz*NG*F + i0 + 1];
    }
    float s = x0+x1;
    for (int off=1; off<64; off<<=1) s += __shfl_xor(s, off);
    float m = s * (1.f/128.f);
    float d0 = x0-m, d1 = x1-m;
    float vv = d0*d0 + d1*d1;
    for (int off=1; off<64; off<<=1) vv += __shfl_xor(vv, off);
    float rs = rsqrtf(vv*(1.f/128.f) + 1e-5f);
    out[i0]   = d0*rs*g[2*lane]   + b[2*lane];
    out[i0+1] = d1*rs*g[2*lane+1] + b[2*lane+1];
}

// ---------------- generic small GEMM: C = A[MxK] @ B[KxN] + bias, opt ReLU ----------------
template<int RELU>
__global__ __launch_bounds__(256) void k_gemm(const float* __restrict__ A, const float* __restrict__ B,
                                              const float* __restrict__ bias, float* __restrict__ C,
                                              int M, int K, int Nc){
    __shared__ float As[32*68];
    __shared__ float Bs[32*64];
    int t = threadIdx.x;
    int rowBase = blockIdx.x*64;
    int colBase = blockIdx.y*64;
    int c0 = (t&15)*4, r0 = (t>>4)*4;
    float acc[4][4];
    #pragma unroll
    for (int i=0;i<4;i++){ acc[i][0]=0.f; acc[i][1]=0.f; acc[i][2]=0.f; acc[i][3]=0.f; }
    for (int kb=0; kb<K; kb+=32){
        #pragma unroll
        for (int i=0;i<8;i++){
            int id = i*256+t; int kk = id&31; int r = id>>5;
            int row = rowBase + r;
            As[kk*68+r] = (row<M) ? A[(size_t)row*K + kb + kk] : 0.f;
        }
        #pragma unroll
        for (int i=0;i<8;i++){
            int id = i*256+t; int c = id&63; int kk = id>>6;
            Bs[kk*64+c] = B[(size_t)(kb+kk)*Nc + colBase + c];
        }
        __syncthreads();
        for (int kk=0;kk<32;kk++){
            float4 a = *(const float4*)&As[kk*68+r0];
            float4 b = *(const float4*)&Bs[kk*64+c0];
            float av[4]={a.x,a.y,a.z,a.w}; float bv[4]={b.x,b.y,b.z,b.w};
            #pragma unroll
            for(int i=0;i<4;i++)
                #pragma unroll
                for(int j=0;j<4;j++) acc[i][j] += av[i]*bv[j];
        }
        __syncthreads();
    }
    for (int i=0;i<4;i++){
        int row = rowBase + r0 + i;
        if (row < M){
            for (int j=0;j<4;j++){
                float v = acc[i][j] + bias[colBase+c0+j];
                if (RELU) v = fmaxf(v, 0.f);
                C[(size_t)row*Nc + colBase + c0 + j] = v;
            }
        }
    }
}

// ---------------- split-K GEMM: part[z] = A[:, zK:(z+1)K] @ B[zK:(z+1)K, :] (no bias) ----------------
__global__ __launch_bounds__(256) void k_gemm_splitk(const float* __restrict__ A, const float* __restrict__ B,
                                                     float* __restrict__ part, int M, int K, int Nc){
    __shared__ float As[32*68];
    __shared__ float Bs[32*64];
    int t = threadIdx.x;
    int rowBase = blockIdx.x*64;
    int colBase = blockIdx.y*64;
    int z = blockIdx.z;
    int kchunk = K / KSPLIT;
    int kbeg = z * kchunk;
    int c0 = (t&15)*4, r0 = (t>>4)*4;
    float acc[4][4];
    #pragma unroll
    for (int i=0;i<4;i++){ acc[i][0]=0.f; acc[i][1]=0.f; acc[i][2]=0.f; acc[i][3]=0.f; }
    for (int kb=kbeg; kb<kbeg+kchunk; kb+=32){
        #pragma unroll
        for (int i=0;i<8;i++){
            int id = i*256+t; int kk = id&31; int r = id>>5;
            int row = rowBase + r;
            As[kk*68+r] = (row<M) ? A[(size_t)row*K + kb + kk] : 0.f;
        }
        #pragma unroll
        for (int i=0;i<8;i++){
            int id = i*256+t; int c = id&63; int kk = id>>6;
            Bs[kk*64+c] = B[(size_t)(kb+kk)*Nc + colBase + c];
        }
        __syncthreads();
        for (int kk=0;kk<32;kk++){
            float4 a = *(const float4*)&As[kk*68+r0];
            float4 b = *(const float4*)&Bs[kk*64+c0];
            float av[4]={a.x,a.y,a.z,a.w}; float bv[4]={b.x,b.y,b.z,b.w};
            #pragma unroll
            for(int i=0;i<4;i++)
                #pragma unroll
                for(int j=0;j<4;j++) acc[i][j] += av[i]*bv[j];
        }
        __syncthreads();
    }
    float* Cp = part + (size_t)z*M*Nc;
    for (int i=0;i<4;i++){
        int row = rowBase + r0 + i;
        if (row < M){
            for (int j=0;j<4;j++)
                Cp[(size_t)row*Nc + colBase + c0 + j] = acc[i][j];
        }
    }
}

// ---------------- fused QKV projections (A shared; blockIdx.z selects weights) ----------------
__global__ __launch_bounds__(256) void k_gemm_qkv(const float* __restrict__ A,
                                                  const float* __restrict__ Wq, const float* __restrict__ Wk,
                                                  const float* __restrict__ Wv, const float* __restrict__ bq,
                                                  const float* __restrict__ bk, const float* __restrict__ bv,
                                                  float* __restrict__ Cq, float* __restrict__ Ck,
                                                  float* __restrict__ Cv){
    __shared__ float As[32*68];
    __shared__ float Bs[32*64];
    int t = threadIdx.x;
    int rowBase = blockIdx.x*64;
    int colBase = blockIdx.y*64;
    int z = blockIdx.z;
    const float* B = (z==0) ? Wq : (z==1) ? Wk : Wv;
    const float* bias = (z==0) ? bq : (z==1) ? bk : bv;
    float* C = (z==0) ? Cq : (z==1) ? Ck : Cv;
    int c0 = (t&15)*4, r0 = (t>>4)*4;
    float acc[4][4];
    #pragma unroll
    for (int i=0;i<4;i++){ acc[i][0]=0.f; acc[i][1]=0.f; acc[i][2]=0.f; acc[i][3]=0.f; }
    for (int kb=0; kb<F; kb+=32){
        #pragma unroll
        for (int i=0;i<8;i++){
            int id = i*256+t; int kk = id&31; int r = id>>5;
            int row = rowBase + r;
            As[kk*68+r] = (row<NG) ? A[(size_t)row*F + kb + kk] : 0.f;
        }
        #pragma unroll
        for (int i=0;i<8;i++){
            int id = i*256+t; int c = id&63; int kk = id>>6;
            Bs[kk*64+c] = B[(size_t)(kb+kk)*F + colBase + c];
        }
        __syncthreads();
        for (int kk=0;kk<32;kk++){
            float4 a = *(const float4*)&As[kk*68+r0];
            float4 b = *(const float4*)&Bs[kk*64+c0];
            float av[4]={a.x,a.y,a.z,a.w}; float bv4[4]={b.x,b.y,b.z,b.w};
            #pragma unroll
            for(int i=0;i<4;i++)
                #pragma unroll
                for(int j=0;j<4;j++) acc[i][j] += av[i]*bv4[j];
        }
        __syncthreads();
    }
    for (int i=0;i<4;i++){
        int row = rowBase + r0 + i;
        if (row < NG){
            for (int j=0;j<4;j++)
                C[(size_t)row*F + colBase + c0 + j] = acc[i][j] + bias[colBase+c0+j];
        }
    }
}

// ---------------- attention: one block per (set, head) ----------------
__global__ __launch_bounds__(256) void k_attn(const float* __restrict__ q, const float* __restrict__ k,
                                              const float* __restrict__ v, float* __restrict__ o){
    __shared__ float Qs[1600], Ks[1600], Vs[1600], Sc[2500];
    int t = threadIdx.x;
    int s = blockIdx.x >> 2; int hh = blockIdx.x & 3;
    for (int idx=t; idx<1600; idx+=256){
        int i = idx>>5, d = idx&31;
        size_t gi = (size_t)(s*50+i)*F + hh*32 + d;
        Qs[idx]=q[gi]; Ks[idx]=k[gi]; Vs[idx]=v[gi];
    }
    __syncthreads();
    for (int idx=t; idx<2500; idx+=256){
        int qi = idx/50, ki = idx%50;
        float acc=0.f;
        #pragma unroll 8
        for (int d=0;d<32;d++) acc += Qs[qi*32+d]*Ks[ki*32+d];
        Sc[idx] = acc * 0.17677669529663687f;   // 1/sqrt(32)
    }
    __syncthreads();
    if (t < 50){
        float m=-1e30f;
        for (int j=0;j<50;j++) m = fmaxf(m, Sc[t*50+j]);
        float sum=0.f;
        for (int j=0;j<50;j++){ float e=__expf(Sc[t*50+j]-m); Sc[t*50+j]=e; sum+=e; }
        float inv = 1.f/sum;
        for (int j=0;j<50;j++) Sc[t*50+j] *= inv;
    }
    __syncthreads();
    for (int idx=t; idx<1600; idx+=256){
        int qi = idx>>5, d = idx&31;
        float acc=0.f;
        #pragma unroll 10
        for (int ki=0;ki<50;ki++) acc += Sc[qi*50+ki]*Vs[ki*32+d];
        o[(size_t)(s*50+qi)*F + hh*32 + d] = acc;
    }
}

// ---------------- MFMA gate: L = h @ Wg_top (bf16 MFMA), out = sig(L+gsi)*zd2 + (1-sig)*h ----------------
__global__ __launch_bounds__(256) void k_gate_mfma(const float* __restrict__ h, const float* __restrict__ Wg,
                                                   const float* __restrict__ gsi, const float* __restrict__ zd2,
                                                   float* __restrict__ out){
    __shared__ short Bw[128*136];   // Wg_top^T as bf16, [n][k], stride 136 (2-way bank alias = free)
    int t = threadIdx.x;
    for (int i=t; i<16384; i+=256){
        int k = i >> 7, n = i & 127;
        Bw[n*136 + k] = f2bs(Wg[(size_t)k*F + n]);
    }
    __syncthreads();
    int lane = t & 63, w = t >> 6;
    int lr = lane & 15, quad = lane >> 4;
    int mrow0 = blockIdx.x*128 + w*32;
    f32x4 acc[2][8];
    #pragma unroll
    for (int i=0;i<2;i++)
        #pragma unroll
        for (int j=0;j<8;j++) acc[i][j] = (f32x4){0.f,0.f,0.f,0.f};
    #pragma unroll
    for (int ks=0; ks<4; ++ks){
        int kb = ks*32 + quad*8;
        short8 a[2];
        #pragma unroll
        for (int mt=0; mt<2; ++mt){
            int row = mrow0 + mt*16 + lr;
            if (row >= NN) row = NN-1;
            const float* p = &h[(size_t)row*F + kb];
            float4 x0 = *(const float4*)p;
            float4 x1 = *(const float4*)(p+4);
            short8 s;
            s[0]=f2bs(x0.x); s[1]=f2bs(x0.y); s[2]=f2bs(x0.z); s[3]=f2bs(x0.w);
            s[4]=f2bs(x1.x); s[5]=f2bs(x1.y); s[6]=f2bs(x1.z); s[7]=f2bs(x1.w);
            a[mt] = s;
        }
        #pragma unroll
        for (int nt=0; nt<8; ++nt){
            short8 b = *(const short8*)&Bw[(nt*16 + lr)*136 + kb];
            acc[0][nt] = __builtin_amdgcn_mfma_f32_16x16x32_bf16(a[0], b, acc[0][nt], 0, 0, 0);
            acc[1][nt] = __builtin_amdgcn_mfma_f32_16x16x32_bf16(a[1], b, acc[1][nt], 0, 0, 0);
        }
    }
    // epilogue: C/D layout col=lane&15, row=quad*4+reg
    #pragma unroll
    for (int mt=0; mt<2; ++mt){
        #pragma unroll
        for (int r=0; r<4; ++r){
            int row = mrow0 + mt*16 + quad*4 + r;
            if (row >= NN) continue;
            int g = row / 50;
            const float* gs = &gsi[(size_t)g*F];
            const float* zs = &zd2[(size_t)g*F];
            const float* hr = &h[(size_t)row*F];
            float* orow = &out[(size_t)row*F];
            #pragma unroll
            for (int nt=0; nt<8; ++nt){
                int col = nt*16 + lr;
                float L = acc[mt][nt][r] + gs[col];
                float gate = 1.f/(1.f + __expf(-L));
                orow[col] = gate*zs[col] + (1.f-gate)*hr[col];
            }
        }
    }
}

extern "C" void kernel_launch(void* const* d_in, const int* in_sizes, int n_in,
                              void* d_out, int out_size, void* d_ws, size_t ws_size,
                              hipStream_t stream) {
    const float* x      = (const float*)d_in[0];
    const int*   ei     = (const int*)d_in[1];
    const float* W_gcn  = (const float*)d_in[4];
    const float* b_gcn  = (const float*)d_in[5];
    const float* bn_g   = (const float*)d_in[6];
    const float* bn_b   = (const float*)d_in[7];
    const float* lnpre_g= (const float*)d_in[8];
    const float* lnpre_b= (const float*)d_in[9];
    const float* Wq     = (const float*)d_in[10];
    const float* bq     = (const float*)d_in[11];
    const float* Wk     = (const float*)d_in[12];
    const float* bk     = (const float*)d_in[13];
    const float* Wv     = (const float*)d_in[14];
    const float* bv     = (const float*)d_in[15];
    const float* Wo     = (const float*)d_in[16];
    const float* bo     = (const float*)d_in[17];
    const float* ln1_g  = (const float*)d_in[18];
    const float* ln1_b  = (const float*)d_in[19];
    const float* W1     = (const float*)d_in[20];
    const float* b1     = (const float*)d_in[21];
    const float* W2     = (const float*)d_in[22];
    const float* b2     = (const float*)d_in[23];
    const float* ln2_g  = (const float*)d_in[24];
    const float* ln2_b  = (const float*)d_in[25];
    const float* Wg     = (const float*)d_in[26];
    const float* bg     = (const float*)d_in[27];
    float* out = (float*)d_out;
    char* ws = (char*)d_ws;

    // workspace layout
    size_t o = 0;
    bf16*  xws   = (bf16*)(ws + o);  o += (size_t)NN*F*2;            // 25.6 MB
    float* h     = (float*)(ws + o); o += (size_t)NN*F*4;            // 51.2 MB
    int*   cnt   = (int*)(ws + o);   o += (size_t)NN*4;
    int*   nstart= (int*)(ws + o);   o += (size_t)NN*4;
    int*   ebuf  = (int*)(ws + o);   o += (size_t)NE*4;              // 6.4 MB
    int*   ebuf2 = (int*)(ws + o);   o += (size_t)NE*4;              // 6.4 MB
    float* dinv  = (float*)(ws + o); o += (size_t)NN*4;
    int*   bcnt  = (int*)(ws + o);   o += 1024*4;
    int*   bstart= (int*)(ws + o);   o += 1024*4;
    int*   bcursor=(int*)(ws + o);   o += 1024*4;
    float* z     = (float*)(ws + o); o += (size_t)NG*F*4;
    float* zn    = (float*)(ws + o); o += (size_t)NG*F*4;
    float* qb    = (float*)(ws + o); o += (size_t)NG*F*4;
    float* kb2   = (float*)(ws + o); o += (size_t)NG*F*4;
    float* vb    = (float*)(ws + o); o += (size_t)NG*F*4;
    float* ao    = (float*)(ws + o); o += (size_t)NG*F*4;
    float* ap    = (float*)(ws + o); o += (size_t)NG*F*4;
    float* zd1   = (float*)(ws + o); o += (size_t)NG*F*4;
    float* ffn1  = (float*)(ws + o); o += (size_t)NG*FFN_DIM*4;      // 8.2 MB
    float* part  = (float*)(ws + o); o += (size_t)KSPLIT*NG*F*4;     // 8.2 MB
    float* zd2   = (float*)(ws + o); o += (size_t)NG*F*4;
    float* gsi   = (float*)(ws + o); o += (size_t)NG*F*4;

    // ---- GCN phase ----
    hipMemsetAsync(cnt, 0, (size_t)NN*4, stream);
    k_count<<<(NE+255)/256, 256, 0, stream>>>(ei, cnt);
    k_dinv_bcnt<<<(NN+255)/256, 256, 0, stream>>>(cnt, dinv, bcnt);
    k_bscan<<<1, 1024, 0, stream>>>(bcnt, bstart, bcursor);
    k_xws<<<(NN+63)/64, 256, 0, stream>>>(x, W_gcn, dinv, xws);
    k_scatter2<<<SC_BLOCKS, 1024, 0, stream>>>(ei, bcursor, ebuf);
    k_sort<<<NB, 256, 0, stream>>>(ebuf, bstart, cnt, nstart, ebuf2);
    k_agg3<<<NN/4, 256, 0, stream>>>(xws, nstart, cnt, dinv, b_gcn, bn_g, bn_b, ebuf2, h);

    // ---- pool + set transformer (fp32, tiny) ----
    k_pool<<<NG/2, 256, 0, stream>>>(h, z);
    k_ln<<<NG/4, 256, 0, stream>>>(z, nullptr, lnpre_g, lnpre_b, zn);
    dim3 gqkv(32, 2, 3);
    k_gemm_qkv<<<gqkv, 256, 0, stream>>>(zn, Wq, Wk, Wv, bq, bk, bv, qb, kb2, vb);
    k_attn<<<NS*4, 256, 0, stream>>>(qb, kb2, vb, ao);
    dim3 g2(32, 2);
    k_gemm<0><<<g2, 256, 0, stream>>>(ao, Wo, bo, ap, NG, F, F);
    k_ln<<<NG/4, 256, 0, stream>>>(z, ap, ln1_g, ln1_b, zd1);
    dim3 gffn1(32, 16);
    k_gemm<1><<<gffn1, 256, 0, stream>>>(zd1, W1, b1, ffn1, NG, F, FFN_DIM);
    dim3 gsk(32, 2, KSPLIT);
    k_gemm_splitk<<<gsk, 256, 0, stream>>>(ffn1, W2, part, NG, FFN_DIM, F);
    k_ln_red<<<NG/4, 256, 0, stream>>>(zd1, part, b2, ln2_g, ln2_b, zd2);
    k_gemm<0><<<g2, 256, 0, stream>>>(zd2, Wg + (size_t)F*F, bg, gsi, NG, F, F);

    // ---- gated fusion -> output ----
    k_gate_mfma<<<782, 256, 0, stream>>>(h, Wg, gsi, zd2, out);
}

// Round 7
// 486.697 us; speedup vs baseline: 3.8605x; 1.0374x over previous
//
#include <hip/hip_runtime.h>
#include <hip/hip_bf16.h>
#include <cstddef>

#define NN 100000
#define NE 1600000
#define NG 2000
#define NS 40
#define INF 64
#define F 128
#define FFN_DIM 1024
#define NB 782            // ceil(100000/128) buckets of 128 nodes
#define SC_BLOCKS 100
#define SC_CHUNK 16000    // 100*16000 = 1.6M edges exactly
#define KSPLIT 8

using bf16 = __hip_bfloat16;
using bf162 = __hip_bfloat162;
typedef __attribute__((ext_vector_type(8))) short short8;
typedef __attribute__((ext_vector_type(4))) float f32x4;
typedef __attribute__((ext_vector_type(2))) float f32x2;

__device__ __forceinline__ short f2bs(float f){
    union { bf16 b; short s; } u; u.b = __float2bfloat16(f); return u.s;
}

// ---------------- degree count ----------------
__global__ __launch_bounds__(256) void k_count(const int* __restrict__ ei, int* __restrict__ cnt){
    int e = blockIdx.x*256 + threadIdx.x;
    if (e < NE) atomicAdd(&cnt[ei[NE + e]], 1);
}

// ---------------- dinv + per-bucket edge counts (fused) ----------------
__global__ __launch_bounds__(256) void k_dinv_bcnt(const int* __restrict__ cnt, float* __restrict__ dinv,
                                                   int* __restrict__ bcnt){
    __shared__ int sd[256];
    int t = threadIdx.x;
    int i = blockIdx.x*256 + t;
    int c = (i < NN) ? cnt[i] : 0;
    if (i < NN) dinv[i] = rsqrtf((float)c + 2.0f);
    sd[t] = c; __syncthreads();
    #pragma unroll
    for (int off=64; off>=1; off>>=1){
        if ((t & 127) < off) sd[t] += sd[t+off];
        __syncthreads();
    }
    if (t == 0)   bcnt[2*blockIdx.x]   = sd[0];
    if (t == 128) bcnt[2*blockIdx.x+1] = sd[128];
}

// ---------------- scan 782 bucket counts -> bstart[783], bcursor ----------------
__global__ __launch_bounds__(1024) void k_bscan(const int* __restrict__ bcnt, int* __restrict__ bstart,
                                                int* __restrict__ bcursor){
    __shared__ int s[1024];
    int t = threadIdx.x;
    int own = (t < NB) ? bcnt[t] : 0;
    s[t] = own; __syncthreads();
    #pragma unroll
    for (int off=1; off<1024; off<<=1){
        int v = (t >= off) ? s[t-off] : 0;
        __syncthreads();
        s[t] += v;
        __syncthreads();
    }
    int excl = s[t] - own;
    if (t <= NB) bstart[t] = excl;     // bstart[782] == NE
    if (t < NB)  bcursor[t] = excl;
}

// ---------------- xws = (x @ W_gcn) * dinv[row], stored fp8 e4m3 (HW cvt) ----------------
__global__ __launch_bounds__(256) void k_xws(const float* __restrict__ x, const float* __restrict__ W,
                                             const float* __restrict__ dinv, unsigned char* __restrict__ xws8){
    __shared__ float As[64*68];    // As[k][r], padded
    __shared__ float Bs[64*128];   // Bs[k][c]
    int t = threadIdx.x;
    int rowBase = blockIdx.x * 64;
    #pragma unroll
    for (int i = 0; i < 32; ++i){ int id = i*256 + t; Bs[id] = W[id]; }
    #pragma unroll
    for (int i = 0; i < 16; ++i){
        int id = i*256 + t; int kk = id & 63; int r = id >> 6;
        int row = rowBase + r;
        As[kk*68 + r] = (row < NN) ? x[(size_t)row*INF + kk] : 0.f;
    }
    __syncthreads();
    int c0 = (t & 31) * 4; int r0 = (t >> 5) * 8;
    float acc[8][4];
    #pragma unroll
    for (int i=0;i<8;i++) { acc[i][0]=0.f; acc[i][1]=0.f; acc[i][2]=0.f; acc[i][3]=0.f; }
    for (int kk = 0; kk < 64; ++kk){
        float4 b = *(const float4*)&Bs[kk*128 + c0];
        float4 a0 = *(const float4*)&As[kk*68 + r0];
        float4 a1 = *(const float4*)&As[kk*68 + r0 + 4];
        float av[8] = {a0.x,a0.y,a0.z,a0.w,a1.x,a1.y,a1.z,a1.w};
        #pragma unroll
        for (int i=0;i<8;i++){
            acc[i][0] += av[i]*b.x; acc[i][1] += av[i]*b.y;
            acc[i][2] += av[i]*b.z; acc[i][3] += av[i]*b.w;
        }
    }
    for (int i=0;i<8;i++){
        int row = rowBase + r0 + i;
        if (row < NN){
            float dv = dinv[row];
            int p = __builtin_amdgcn_cvt_pk_fp8_f32(acc[i][0]*dv, acc[i][1]*dv, 0, false);
            p     = __builtin_amdgcn_cvt_pk_fp8_f32(acc[i][2]*dv, acc[i][3]*dv, p, true);
            *(int*)&xws8[(size_t)row*F + c0] = p;
        }
    }
}

// ---------------- binned scatter: pack (row<<7|col&127) into bucket regions ----------------
__global__ __launch_bounds__(1024) void k_scatter2(const int* __restrict__ ei, int* __restrict__ bcursor,
                                                   int* __restrict__ ebuf){
    __shared__ int lh[NB];
    __shared__ int lb[NB];
    int t = threadIdx.x;
    int base = blockIdx.x * SC_CHUNK;
    for (int b=t; b<NB; b+=1024) lh[b] = 0;
    __syncthreads();
    // pass 1: local histogram
    for (int i=t; i<SC_CHUNK; i+=1024){
        int c = ei[NE + base + i];
        atomicAdd(&lh[c>>7], 1);
    }
    __syncthreads();
    // reserve global runs
    for (int b=t; b<NB; b+=1024){
        int n = lh[b];
        lb[b] = n ? atomicAdd(&bcursor[b], n) : 0;
        lh[b] = 0;
    }
    __syncthreads();
    // pass 2: place
    for (int i=t; i<SC_CHUNK; i+=1024){
        int r = ei[base + i];
        int c = ei[NE + base + i];
        int b = c >> 7;
        int rk = atomicAdd(&lh[b], 1);
        ebuf[lb[b] + rk] = (r << 7) | (c & 127);
    }
}

// ---------------- per-bucket counting sort -> node-sorted rows + per-node CSR starts ----------------
__global__ __launch_bounds__(256) void k_sort(const int* __restrict__ ebuf, const int* __restrict__ bstart,
                                              const int* __restrict__ cnt, int* __restrict__ nstart,
                                              int* __restrict__ ebuf2){
    __shared__ int s[128];
    __shared__ int lcur[128];
    int t = threadIdx.x;
    int b = blockIdx.x;
    int n0 = b * 128;
    int node = n0 + t;
    int c = 0;
    if (t < 128) c = (node < NN) ? cnt[node] : 0;
    if (t < 128) s[t] = c;
    __syncthreads();
    #pragma unroll
    for (int off=1; off<128; off<<=1){
        int v = (t >= off && t < 128) ? s[t-off] : 0;
        __syncthreads();
        if (t < 128) s[t] += v;
        __syncthreads();
    }
    int e0 = bstart[b];
    if (t < 128){
        int excl = s[t] - c;
        lcur[t] = excl;
        if (node < NN) nstart[node] = e0 + excl;
    }
    __syncthreads();
    int nE = bstart[b+1] - e0;
    for (int i=t; i<nE; i+=256){
        int v = ebuf[e0 + i];
        int nl = v & 127;
        int rk = atomicAdd(&lcur[nl], 1);
        ebuf2[e0 + rk] = v >> 7;     // row index
    }
}

// ---------------- per-node CSR gather (fp8 rows) + GCN epilogue + BN + ReLU -> h (fp32) ----------------
__global__ __launch_bounds__(256) void k_agg3(const unsigned char* __restrict__ xws8, const int* __restrict__ nstart,
                                              const int* __restrict__ cnt, const float* __restrict__ dinv,
                                              const float* __restrict__ b_gcn, const float* __restrict__ bn_g,
                                              const float* __restrict__ bn_b, const int* __restrict__ ebuf2,
                                              float* __restrict__ h){
    int t = threadIdx.x; int lane = t & 63;
    int node = blockIdx.x*4 + (t>>6);
    int s0 = nstart[node]; int dg = cnt[node]; float dv = dinv[node];
    const unsigned short* xw8 = (const unsigned short*)xws8;
    float a0=0.f, a1=0.f;
    int j=0;
    for (; j+4<=dg; j+=4){
        int r0 = ebuf2[s0+j], r1 = ebuf2[s0+j+1], r2 = ebuf2[s0+j+2], r3 = ebuf2[s0+j+3];
        int u0 = xw8[(size_t)r0*64 + lane];
        int u1 = xw8[(size_t)r1*64 + lane];
        int u2 = xw8[(size_t)r2*64 + lane];
        int u3 = xw8[(size_t)r3*64 + lane];
        f32x2 f0 = __builtin_amdgcn_cvt_pk_f32_fp8(u0, false);
        f32x2 f1 = __builtin_amdgcn_cvt_pk_f32_fp8(u1, false);
        f32x2 f2 = __builtin_amdgcn_cvt_pk_f32_fp8(u2, false);
        f32x2 f3 = __builtin_amdgcn_cvt_pk_f32_fp8(u3, false);
        a0 += (f0.x + f1.x) + (f2.x + f3.x);
        a1 += (f0.y + f1.y) + (f2.y + f3.y);
    }
    for (; j<dg; ++j){
        int r0 = ebuf2[s0+j];
        int u0 = xw8[(size_t)r0*64 + lane];
        f32x2 f0 = __builtin_amdgcn_cvt_pk_f32_fp8(u0, false);
        a0 += f0.x; a1 += f0.y;
    }
    int us = xw8[(size_t)node*64 + lane];
    f32x2 fs = __builtin_amdgcn_cvt_pk_f32_fp8(us, false);
    float p0 = dv*(a0 + 2.f*fs.x) + b_gcn[2*lane];
    float p1 = dv*(a1 + 2.f*fs.y) + b_gcn[2*lane+1];
    float bns = rsqrtf(1.f + 1e-5f);
    p0 = p0*bns*bn_g[2*lane]   + bn_b[2*lane];
    p1 = p1*bns*bn_g[2*lane+1] + bn_b[2*lane+1];
    h[(size_t)node*F + 2*lane]   = fmaxf(p0, 0.f);
    h[(size_t)node*F + 2*lane+1] = fmaxf(p1, 0.f);
}

// ---------------- mean pool (50 nodes/graph) ----------------
__global__ __launch_bounds__(256) void k_pool(const float* __restrict__ h, float* __restrict__ z){
    int t = threadIdx.x;
    int g = blockIdx.x*2 + (t>>7);
    int f = t & 127;
    float s = 0.f;
    const float* p = h + (size_t)g*50*F + f;
    #pragma unroll 5
    for (int i=0;i<50;i++) s += p[i*F];
    z[g*F+f] = s / 50.0f;
}

// ---------------- LayerNorm (optional residual add) ----------------
__global__ __launch_bounds__(256) void k_ln(const float* __restrict__ A, const float* __restrict__ R,
                                            const float* __restrict__ g, const float* __restrict__ b,
                                            float* __restrict__ out){
    int t = threadIdx.x; int lane = t&63;
    int row = blockIdx.x*4 + (t>>6);
    int i0 = row*F + 2*lane;
    float x0 = A[i0], x1 = A[i0+1];
    if (R){ x0 += R[i0]; x1 += R[i0+1]; }
    float s = x0+x1;
    for (int off=1; off<64; off<<=1) s += __shfl_xor(s, off);
    float m = s * (1.f/128.f);
    float d0 = x0-m, d1 = x1-m;
    float vv = d0*d0 + d1*d1;
    for (int off=1; off<64; off<<=1) vv += __shfl_xor(vv, off);
    float rs = rsqrtf(vv*(1.f/128.f) + 1e-5f);
    out[i0]   = d0*rs*g[2*lane]   + b[2*lane];
    out[i0+1] = d1*rs*g[2*lane+1] + b[2*lane+1];
}

// ---------------- LN over (A + sum of KSPLIT partials + bias) ----------------
__global__ __launch_bounds__(256) void k_ln_red(const float* __restrict__ A, const float* __restrict__ part,
                                                const float* __restrict__ bias, const float* __restrict__ g,
                                                const float* __restrict__ b, float* __restrict__ out){
    int t = threadIdx.x; int lane = t&63;
    int row = blockIdx.x*4 + (t>>6);
    int i0 = row*F + 2*lane;
    float x0 = A[i0] + bias[2*lane], x1 = A[i0+1] + bias[2*lane+1];
    #pragma unroll
    for (int zz=0; zz<KSPLIT; ++zz){
        x0 += part[(size_t)zz*NG*F + i0];
        x1 += part[(size_t)zz*NG*F + i0 + 1];
    }
    float s = x0+x1;
    for (int off=1; off<64; off<<=1) s += __shfl_xor(s, off);
    float m = s * (1.f/128.f);
    float d0 = x0-m, d1 = x1-m;
    float vv = d0*d0 + d1*d1;
    for (int off=1; off<64; off<<=1) vv += __shfl_xor(vv, off);
    float rs = rsqrtf(vv*(1.f/128.f) + 1e-5f);
    out[i0]   = d0*rs*g[2*lane]   + b[2*lane];
    out[i0+1] = d1*rs*g[2*lane+1] + b[2*lane+1];
}

// ---------------- generic small GEMM: C = A[MxK] @ B[KxN] + bias, opt ReLU ----------------
template<int RELU>
__global__ __launch_bounds__(256) void k_gemm(const float* __restrict__ A, const float* __restrict__ B,
                                              const float* __restrict__ bias, float* __restrict__ C,
                                              int M, int K, int Nc){
    __shared__ float As[32*68];
    __shared__ float Bs[32*64];
    int t = threadIdx.x;
    int rowBase = blockIdx.x*64;
    int colBase = blockIdx.y*64;
    int c0 = (t&15)*4, r0 = (t>>4)*4;
    float acc[4][4];
    #pragma unroll
    for (int i=0;i<4;i++){ acc[i][0]=0.f; acc[i][1]=0.f; acc[i][2]=0.f; acc[i][3]=0.f; }
    for (int kb=0; kb<K; kb+=32){
        #pragma unroll
        for (int i=0;i<8;i++){
            int id = i*256+t; int kk = id&31; int r = id>>5;
            int row = rowBase + r;
            As[kk*68+r] = (row<M) ? A[(size_t)row*K + kb + kk] : 0.f;
        }
        #pragma unroll
        for (int i=0;i<8;i++){
            int id = i*256+t; int c = id&63; int kk = id>>6;
            Bs[kk*64+c] = B[(size_t)(kb+kk)*Nc + colBase + c];
        }
        __syncthreads();
        for (int kk=0;kk<32;kk++){
            float4 a = *(const float4*)&As[kk*68+r0];
            float4 b = *(const float4*)&Bs[kk*64+c0];
            float av[4]={a.x,a.y,a.z,a.w}; float bv[4]={b.x,b.y,b.z,b.w};
            #pragma unroll
            for(int i=0;i<4;i++)
                #pragma unroll
                for(int j=0;j<4;j++) acc[i][j] += av[i]*bv[j];
        }
        __syncthreads();
    }
    for (int i=0;i<4;i++){
        int row = rowBase + r0 + i;
        if (row < M){
            for (int j=0;j<4;j++){
                float v = acc[i][j] + bias[colBase+c0+j];
                if (RELU) v = fmaxf(v, 0.f);
                C[(size_t)row*Nc + colBase + c0 + j] = v;
            }
        }
    }
}

// ---------------- split-K GEMM: part[z] = A[:, zK:(z+1)K] @ B[zK:(z+1)K, :] (no bias) ----------------
__global__ __launch_bounds__(256) void k_gemm_splitk(const float* __restrict__ A, const float* __restrict__ B,
                                                     float* __restrict__ part, int M, int K, int Nc){
    __shared__ float As[32*68];
    __shared__ float Bs[32*64];
    int t = threadIdx.x;
    int rowBase = blockIdx.x*64;
    int colBase = blockIdx.y*64;
    int z = blockIdx.z;
    int kchunk = K / KSPLIT;
    int kbeg = z * kchunk;
    int c0 = (t&15)*4, r0 = (t>>4)*4;
    float acc[4][4];
    #pragma unroll
    for (int i=0;i<4;i++){ acc[i][0]=0.f; acc[i][1]=0.f; acc[i][2]=0.f; acc[i][3]=0.f; }
    for (int kb=kbeg; kb<kbeg+kchunk; kb+=32){
        #pragma unroll
        for (int i=0;i<8;i++){
            int id = i*256+t; int kk = id&31; int r = id>>5;
            int row = rowBase + r;
            As[kk*68+r] = (row<M) ? A[(size_t)row*K + kb + kk] : 0.f;
        }
        #pragma unroll
        for (int i=0;i<8;i++){
            int id = i*256+t; int c = id&63; int kk = id>>6;
            Bs[kk*64+c] = B[(size_t)(kb+kk)*Nc + colBase + c];
        }
        __syncthreads();
        for (int kk=0;kk<32;kk++){
            float4 a = *(const float4*)&As[kk*68+r0];
            float4 b = *(const float4*)&Bs[kk*64+c0];
            float av[4]={a.x,a.y,a.z,a.w}; float bv[4]={b.x,b.y,b.z,b.w};
            #pragma unroll
            for(int i=0;i<4;i++)
                #pragma unroll
                for(int j=0;j<4;j++) acc[i][j] += av[i]*bv[j];
        }
        __syncthreads();
    }
    float* Cp = part + (size_t)z*M*Nc;
    for (int i=0;i<4;i++){
        int row = rowBase + r0 + i;
        if (row < M){
            for (int j=0;j<4;j++)
                Cp[(size_t)row*Nc + colBase + c0 + j] = acc[i][j];
        }
    }
}

// ---------------- fused QKV projections (A shared; blockIdx.z selects weights) ----------------
__global__ __launch_bounds__(256) void k_gemm_qkv(const float* __restrict__ A,
                                                  const float* __restrict__ Wq, const float* __restrict__ Wk,
                                                  const float* __restrict__ Wv, const float* __restrict__ bq,
                                                  const float* __restrict__ bk, const float* __restrict__ bv,
                                                  float* __restrict__ Cq, float* __restrict__ Ck,
                                                  float* __restrict__ Cv){
    __shared__ float As[32*68];
    __shared__ float Bs[32*64];
    int t = threadIdx.x;
    int rowBase = blockIdx.x*64;
    int colBase = blockIdx.y*64;
    int z = blockIdx.z;
    const float* B = (z==0) ? Wq : (z==1) ? Wk : Wv;
    const float* bias = (z==0) ? bq : (z==1) ? bk : bv;
    float* C = (z==0) ? Cq : (z==1) ? Ck : Cv;
    int c0 = (t&15)*4, r0 = (t>>4)*4;
    float acc[4][4];
    #pragma unroll
    for (int i=0;i<4;i++){ acc[i][0]=0.f; acc[i][1]=0.f; acc[i][2]=0.f; acc[i][3]=0.f; }
    for (int kb=0; kb<F; kb+=32){
        #pragma unroll
        for (int i=0;i<8;i++){
            int id = i*256+t; int kk = id&31; int r = id>>5;
            int row = rowBase + r;
            As[kk*68+r] = (row<NG) ? A[(size_t)row*F + kb + kk] : 0.f;
        }
        #pragma unroll
        for (int i=0;i<8;i++){
            int id = i*256+t; int c = id&63; int kk = id>>6;
            Bs[kk*64+c] = B[(size_t)(kb+kk)*F + colBase + c];
        }
        __syncthreads();
        for (int kk=0;kk<32;kk++){
            float4 a = *(const float4*)&As[kk*68+r0];
            float4 b = *(const float4*)&Bs[kk*64+c0];
            float av[4]={a.x,a.y,a.z,a.w}; float bv4[4]={b.x,b.y,b.z,b.w};
            #pragma unroll
            for(int i=0;i<4;i++)
                #pragma unroll
                for(int j=0;j<4;j++) acc[i][j] += av[i]*bv4[j];
        }
        __syncthreads();
    }
    for (int i=0;i<4;i++){
        int row = rowBase + r0 + i;
        if (row < NG){
            for (int j=0;j<4;j++)
                C[(size_t)row*F + colBase + c0 + j] = acc[i][j] + bias[colBase+c0+j];
        }
    }
}

// ---------------- attention: one block per (set, head) ----------------
__global__ __launch_bounds__(256) void k_attn(const float* __restrict__ q, const float* __restrict__ k,
                                              const float* __restrict__ v, float* __restrict__ o){
    __shared__ float Qs[1600], Ks[1600], Vs[1600], Sc[2500];
    int t = threadIdx.x;
    int s = blockIdx.x >> 2; int hh = blockIdx.x & 3;
    for (int idx=t; idx<1600; idx+=256){
        int i = idx>>5, d = idx&31;
        size_t gi = (size_t)(s*50+i)*F + hh*32 + d;
        Qs[idx]=q[gi]; Ks[idx]=k[gi]; Vs[idx]=v[gi];
    }
    __syncthreads();
    for (int idx=t; idx<2500; idx+=256){
        int qi = idx/50, ki = idx%50;
        float acc=0.f;
        #pragma unroll 8
        for (int d=0;d<32;d++) acc += Qs[qi*32+d]*Ks[ki*32+d];
        Sc[idx] = acc * 0.17677669529663687f;   // 1/sqrt(32)
    }
    __syncthreads();
    if (t < 50){
        float m=-1e30f;
        for (int j=0;j<50;j++) m = fmaxf(m, Sc[t*50+j]);
        float sum=0.f;
        for (int j=0;j<50;j++){ float e=__expf(Sc[t*50+j]-m); Sc[t*50+j]=e; sum+=e; }
        float inv = 1.f/sum;
        for (int j=0;j<50;j++) Sc[t*50+j] *= inv;
    }
    __syncthreads();
    for (int idx=t; idx<1600; idx+=256){
        int qi = idx>>5, d = idx&31;
        float acc=0.f;
        #pragma unroll 10
        for (int ki=0;ki<50;ki++) acc += Sc[qi*50+ki]*Vs[ki*32+d];
        o[(size_t)(s*50+qi)*F + hh*32 + d] = acc;
    }
}

// ---------------- MFMA gate: L = h @ Wg_top (bf16 MFMA), out = sig(L+gsi)*zd2 + (1-sig)*h ----------------
__global__ __launch_bounds__(256) void k_gate_mfma(const float* __restrict__ h, const float* __restrict__ Wg,
                                                   const float* __restrict__ gsi, const float* __restrict__ zd2,
                                                   float* __restrict__ out){
    __shared__ short Bw[128*136];   // Wg_top^T as bf16, [n][k], stride 136 (2-way bank alias = free)
    int t = threadIdx.x;
    for (int i=t; i<16384; i+=256){
        int k = i >> 7, n = i & 127;
        Bw[n*136 + k] = f2bs(Wg[(size_t)k*F + n]);
    }
    __syncthreads();
    int lane = t & 63, w = t >> 6;
    int lr = lane & 15, quad = lane >> 4;
    int mrow0 = blockIdx.x*128 + w*32;
    f32x4 acc[2][8];
    #pragma unroll
    for (int i=0;i<2;i++)
        #pragma unroll
        for (int j=0;j<8;j++) acc[i][j] = (f32x4){0.f,0.f,0.f,0.f};
    #pragma unroll
    for (int ks=0; ks<4; ++ks){
        int kb = ks*32 + quad*8;
        short8 a[2];
        #pragma unroll
        for (int mt=0; mt<2; ++mt){
            int row = mrow0 + mt*16 + lr;
            if (row >= NN) row = NN-1;
            const float* p = &h[(size_t)row*F + kb];
            float4 x0 = *(const float4*)p;
            float4 x1 = *(const float4*)(p+4);
            short8 s;
            s[0]=f2bs(x0.x); s[1]=f2bs(x0.y); s[2]=f2bs(x0.z); s[3]=f2bs(x0.w);
            s[4]=f2bs(x1.x); s[5]=f2bs(x1.y); s[6]=f2bs(x1.z); s[7]=f2bs(x1.w);
            a[mt] = s;
        }
        #pragma unroll
        for (int nt=0; nt<8; ++nt){
            short8 b = *(const short8*)&Bw[(nt*16 + lr)*136 + kb];
            acc[0][nt] = __builtin_amdgcn_mfma_f32_16x16x32_bf16(a[0], b, acc[0][nt], 0, 0, 0);
            acc[1][nt] = __builtin_amdgcn_mfma_f32_16x16x32_bf16(a[1], b, acc[1][nt], 0, 0, 0);
        }
    }
    // epilogue: C/D layout col=lane&15, row=quad*4+reg
    #pragma unroll
    for (int mt=0; mt<2; ++mt){
        #pragma unroll
        for (int r=0; r<4; ++r){
            int row = mrow0 + mt*16 + quad*4 + r;
            if (row >= NN) continue;
            int g = row / 50;
            const float* gs = &gsi[(size_t)g*F];
            const float* zs = &zd2[(size_t)g*F];
            const float* hr = &h[(size_t)row*F];
            float* orow = &out[(size_t)row*F];
            #pragma unroll
            for (int nt=0; nt<8; ++nt){
                int col = nt*16 + lr;
                float L = acc[mt][nt][r] + gs[col];
                float gate = 1.f/(1.f + __expf(-L));
                orow[col] = gate*zs[col] + (1.f-gate)*hr[col];
            }
        }
    }
}

extern "C" void kernel_launch(void* const* d_in, const int* in_sizes, int n_in,
                              void* d_out, int out_size, void* d_ws, size_t ws_size,
                              hipStream_t stream) {
    const float* x      = (const float*)d_in[0];
    const int*   ei     = (const int*)d_in[1];
    const float* W_gcn  = (const float*)d_in[4];
    const float* b_gcn  = (const float*)d_in[5];
    const float* bn_g   = (const float*)d_in[6];
    const float* bn_b   = (const float*)d_in[7];
    const float* lnpre_g= (const float*)d_in[8];
    const float* lnpre_b= (const float*)d_in[9];
    const float* Wq     = (const float*)d_in[10];
    const float* bq     = (const float*)d_in[11];
    const float* Wk     = (const float*)d_in[12];
    const float* bk     = (const float*)d_in[13];
    const float* Wv     = (const float*)d_in[14];
    const float* bv     = (const float*)d_in[15];
    const float* Wo     = (const float*)d_in[16];
    const float* bo     = (const float*)d_in[17];
    const float* ln1_g  = (const float*)d_in[18];
    const float* ln1_b  = (const float*)d_in[19];
    const float* W1     = (const float*)d_in[20];
    const float* b1     = (const float*)d_in[21];
    const float* W2     = (const float*)d_in[22];
    const float* b2     = (const float*)d_in[23];
    const float* ln2_g  = (const float*)d_in[24];
    const float* ln2_b  = (const float*)d_in[25];
    const float* Wg     = (const float*)d_in[26];
    const float* bg     = (const float*)d_in[27];
    float* out = (float*)d_out;
    char* ws = (char*)d_ws;

    // workspace layout
    size_t o = 0;
    unsigned char* xws8 = (unsigned char*)(ws + o); o += (size_t)NN*F; // 12.8 MB (fp8)
    float* h     = (float*)(ws + o); o += (size_t)NN*F*4;            // 51.2 MB
    int*   cnt   = (int*)(ws + o);   o += (size_t)NN*4;
    int*   nstart= (int*)(ws + o);   o += (size_t)NN*4;
    int*   ebuf  = (int*)(ws + o);   o += (size_t)NE*4;              // 6.4 MB
    int*   ebuf2 = (int*)(ws + o);   o += (size_t)NE*4;              // 6.4 MB
    float* dinv  = (float*)(ws + o); o += (size_t)NN*4;
    int*   bcnt  = (int*)(ws + o);   o += 1024*4;
    int*   bstart= (int*)(ws + o);   o += 1024*4;
    int*   bcursor=(int*)(ws + o);   o += 1024*4;
    float* z     = (float*)(ws + o); o += (size_t)NG*F*4;
    float* zn    = (float*)(ws + o); o += (size_t)NG*F*4;
    float* qb    = (float*)(ws + o); o += (size_t)NG*F*4;
    float* kb2   = (float*)(ws + o); o += (size_t)NG*F*4;
    float* vb    = (float*)(ws + o); o += (size_t)NG*F*4;
    float* ao    = (float*)(ws + o); o += (size_t)NG*F*4;
    float* ap    = (float*)(ws + o); o += (size_t)NG*F*4;
    float* zd1   = (float*)(ws + o); o += (size_t)NG*F*4;
    float* ffn1  = (float*)(ws + o); o += (size_t)NG*FFN_DIM*4;      // 8.2 MB
    float* part  = (float*)(ws + o); o += (size_t)KSPLIT*NG*F*4;     // 8.2 MB
    float* zd2   = (float*)(ws + o); o += (size_t)NG*F*4;
    float* gsi   = (float*)(ws + o); o += (size_t)NG*F*4;

    // ---- GCN phase ----
    hipMemsetAsync(cnt, 0, (size_t)NN*4, stream);
    k_count<<<(NE+255)/256, 256, 0, stream>>>(ei, cnt);
    k_dinv_bcnt<<<(NN+255)/256, 256, 0, stream>>>(cnt, dinv, bcnt);
    k_bscan<<<1, 1024, 0, stream>>>(bcnt, bstart, bcursor);
    k_xws<<<(NN+63)/64, 256, 0, stream>>>(x, W_gcn, dinv, xws8);
    k_scatter2<<<SC_BLOCKS, 1024, 0, stream>>>(ei, bcursor, ebuf);
    k_sort<<<NB, 256, 0, stream>>>(ebuf, bstart, cnt, nstart, ebuf2);
    k_agg3<<<NN/4, 256, 0, stream>>>(xws8, nstart, cnt, dinv, b_gcn, bn_g, bn_b, ebuf2, h);

    // ---- pool + set transformer (fp32, tiny) ----
    k_pool<<<NG/2, 256, 0, stream>>>(h, z);
    k_ln<<<NG/4, 256, 0, stream>>>(z, nullptr, lnpre_g, lnpre_b, zn);
    dim3 gqkv(32, 2, 3);
    k_gemm_qkv<<<gqkv, 256, 0, stream>>>(zn, Wq, Wk, Wv, bq, bk, bv, qb, kb2, vb);
    k_attn<<<NS*4, 256, 0, stream>>>(qb, kb2, vb, ao);
    dim3 g2(32, 2);
    k_gemm<0><<<g2, 256, 0, stream>>>(ao, Wo, bo, ap, NG, F, F);
    k_ln<<<NG/4, 256, 0, stream>>>(z, ap, ln1_g, ln1_b, zd1);
    dim3 gffn1(32, 16);
    k_gemm<1><<<gffn1, 256, 0, stream>>>(zd1, W1, b1, ffn1, NG, F, FFN_DIM);
    dim3 gsk(32, 2, KSPLIT);
    k_gemm_splitk<<<gsk, 256, 0, stream>>>(ffn1, W2, part, NG, FFN_DIM, F);
    k_ln_red<<<NG/4, 256, 0, stream>>>(zd1, part, b2, ln2_g, ln2_b, zd2);
    k_gemm<0><<<g2, 256, 0, stream>>>(zd2, Wg + (size_t)F*F, bg, gsi, NG, F, F);

    // ---- gated fusion -> output ----
    k_gate_mfma<<<782, 256, 0, stream>>>(h, Wg, gsi, zd2, out);
}